// Round 13
// baseline (30550.244 us; speedup 1.0000x reference)
//
#include <hip/hip_runtime.h>
#include <cstdint>
#include <cstddef>

typedef __bf16 bf16;
typedef __bf16 bf16x8 __attribute__((ext_vector_type(8)));
typedef __bf16 bf16x4 __attribute__((ext_vector_type(4)));
typedef float f32x4 __attribute__((ext_vector_type(4)));

static constexpr int D = 4096;
static constexpr int S = 4096;
static constexpr int T = 256;
static constexpr int H = 32;
static constexpr int F = 16384;

__device__ __forceinline__ void gload16(const void* g, void* l) {
  __builtin_amdgcn_global_load_lds((const __attribute__((address_space(1))) void*)g,
                                   (__attribute__((address_space(3))) void*)l, 16, 0, 0);
}

#define MFMA16(a, b, c) __builtin_amdgcn_mfma_f32_16x16x32_bf16((a), (b), (c), 0, 0, 0)

// ---------------- elementwise f32 -> bf16 ----------------
__global__ __launch_bounds__(256) void k_cvt(const float* __restrict__ in, bf16* __restrict__ out, int n) {
  int i = (blockIdx.x * 256 + threadIdx.x) * 4;
  if (i >= n) return;
  float4 v = *(const float4*)(in + i);
  bf16x4 o = { (bf16)v.x, (bf16)v.y, (bf16)v.z, (bf16)v.w };
  *(bf16x4*)(out + i) = o;
}

// ---------------- transpose+cvt: f32 [R][C] (row stride ldin) -> bf16 [C][R], 64x64 tiles --------
__global__ __launch_bounds__(256) void k_tc(const float* __restrict__ in, bf16* __restrict__ out,
                                            int R, int C, int ldin) {
  __shared__ float tile[64][65];
  const int c0 = blockIdx.x * 64, r0 = blockIdx.y * 64;
  const int x = threadIdx.x, y = threadIdx.y;  // block (64,4)
  #pragma unroll
  for (int i = 0; i < 16; i++) {
    const int yy = y + 4 * i;
    tile[yy][x] = in[(size_t)(r0 + yy) * ldin + c0 + x];
  }
  __syncthreads();
  #pragma unroll
  for (int i = 0; i < 16; i++) {
    const int yy = y + 4 * i;
    out[(size_t)(c0 + yy) * R + r0 + x] = (bf16)tile[x][yy];
  }
}

// ---------------- transpose bf16 [R][C] (row stride ldin) -> [C][R] ----------------
__global__ __launch_bounds__(256) void k_tb(const bf16* __restrict__ in, bf16* __restrict__ out,
                                            int R, int C, int ldin) {
  __shared__ bf16 tile[32][33];
  int c0 = blockIdx.x * 32, r0 = blockIdx.y * 32;
  int x = threadIdx.x, y = threadIdx.y;
  #pragma unroll
  for (int yy = y; yy < 32; yy += 8)
    tile[yy][x] = in[(size_t)(r0 + yy) * ldin + c0 + x];
  __syncthreads();
  #pragma unroll
  for (int yy = y; yy < 32; yy += 8)
    out[(size_t)(c0 + yy) * R + r0 + x] = tile[x][yy];
}

// ---------------- rmsnorm over 4096, bf16 in (row stride ldin) -> bf16 out, scaled ---------------
__global__ __launch_bounds__(256) void k_rms(const bf16* __restrict__ in, const float* __restrict__ w,
                                             bf16* __restrict__ out, int ldin, float sc) {
  const int row = blockIdx.x, t = threadIdx.x;
  const bf16* x = in + (size_t)row * ldin;
  float xv[16];
  float ss = 0.f;
  #pragma unroll
  for (int i = 0; i < 2; i++) {
    bf16x8 b = *(const bf16x8*)(x + t * 8 + i * 2048);
    #pragma unroll
    for (int j = 0; j < 8; j++) { xv[i * 8 + j] = (float)b[j]; ss += xv[i * 8 + j] * xv[i * 8 + j]; }
  }
  #pragma unroll
  for (int off = 1; off < 64; off <<= 1) ss += __shfl_xor(ss, off, 64);
  __shared__ float red[4];
  if ((t & 63) == 0) red[t >> 6] = ss;
  __syncthreads();
  float rms = rsqrtf((red[0] + red[1] + red[2] + red[3]) * (1.f / 4096.f) + 1e-6f) * sc;
  #pragma unroll
  for (int i = 0; i < 2; i++) {
    float4 w0 = *(const float4*)(w + t * 8 + i * 2048);
    float4 w1 = *(const float4*)(w + t * 8 + i * 2048 + 4);
    bf16x8 ov;
    ov[0] = (bf16)(xv[i * 8 + 0] * rms * w0.x); ov[1] = (bf16)(xv[i * 8 + 1] * rms * w0.y);
    ov[2] = (bf16)(xv[i * 8 + 2] * rms * w0.z); ov[3] = (bf16)(xv[i * 8 + 3] * rms * w0.w);
    ov[4] = (bf16)(xv[i * 8 + 4] * rms * w1.x); ov[5] = (bf16)(xv[i * 8 + 5] * rms * w1.y);
    ov[6] = (bf16)(xv[i * 8 + 6] * rms * w1.z); ov[7] = (bf16)(xv[i * 8 + 7] * rms * w1.w);
    *(bf16x8*)(out + (size_t)row * 4096 + t * 8 + i * 2048) = ov;
  }
}

// supertile XCD mapping (bijective): by = (xcd%XGM)*BYG + oidx%BYG ; bx = (xcd/XGM)*BXG + oidx/BYG
__device__ __forceinline__ void xcd_map(int orig, int XGM, int BYG, int BXG, int& by, int& bx) {
  const int xcd = orig & 7, oidx = orig >> 3;
  by = (xcd % XGM) * BYG + oidx % BYG;
  bx = (xcd / XGM) * BXG + oidx / BYG;
}

// ======= 256x256 GEMM, BK=32 2-phase, 64KB LDS -> 2 blocks/CU (16 waves) =======
// P0: {12 ds_read (8 A + 4 B frags), barrier, 16 MFMA(nf0,1)}
// P1: {stage tile t+2 (4 gloads), vmcnt(4), barrier, 16 MFMA(nf2,3)}
// MODE 0: f32 out; 1: bf16 out; 2: f32 = v+res; 3: f32 = v+res AND bf16 dual write
template <int MODE>
__global__ __launch_bounds__(512, 4) void k_gemm2(const bf16* __restrict__ A, const bf16* __restrict__ BT,
                                                  float* __restrict__ Cf, bf16* __restrict__ Cb,
                                                  const float* __restrict__ res,
                                                  int M, int N, int K, int XGM, int BYG, int BXG) {
  __shared__ bf16 LA[2][256 * 32];  // [dbuf][row*32+col]  (16KB each)
  __shared__ bf16 LB[2][256 * 32];
  int by, bx;
  xcd_map(blockIdx.x, XGM, BYG, BXG, by, bx);
  const size_t m0 = (size_t)by * 256, n0 = (size_t)bx * 256;
  const int t = threadIdx.x;
  const int w = t >> 6, lane = t & 63;
  const int wm = w >> 2, wn = w & 3;
  const int g = lane >> 4, r15 = lane & 15;
  const int nt = K >> 5;  // BK=32; always even
  const int sr0 = t >> 2, ss0 = t & 3;
  const int sr1 = (t + 512) >> 2, ss1 = (t + 512) & 3;
  const int sc0 = ((ss0 ^ ((sr0 >> 1) & 3)) << 3);
  const int sc1 = ((ss1 ^ ((sr1 >> 1) & 3)) << 3);
  f32x4 acc[8][4] = {};

  auto stA = [&](int db, int st) {
    const bf16* src = A + m0 * K + (size_t)st * 32;
    gload16(src + (size_t)sr0 * K + sc0, &LA[db][t * 8]);
    gload16(src + (size_t)sr1 * K + sc1, &LA[db][(t + 512) * 8]);
  };
  auto stB = [&](int db, int st) {
    const bf16* src = BT + n0 * K + (size_t)st * 32;
    gload16(src + (size_t)sr0 * K + sc0, &LB[db][t * 8]);
    gload16(src + (size_t)sr1 * K + sc1, &LB[db][(t + 512) * 8]);
  };

  // prologue: T0{A,B} + T1{A,B} = 8 loads/thread
  stA(0, 0); stB(0, 0); stA(1, 1); stB(1, 1);
  asm volatile("s_waitcnt vmcnt(4)" ::: "memory");  // T0 landed
  __builtin_amdgcn_s_barrier();

  const int arow = wm * 128;

#define GEMM_T32(DD, TC)                                                                      \
  {                                                                                           \
    const int t2 = ((TC) + 2 < nt) ? (TC) + 2 : nt - 1;                                       \
    bf16x8 af[8], b0, b1, b2, b3;                                                             \
    /* phase 0: reads + MFMA nf0,1 */                                                         \
    _Pragma("unroll")                                                                         \
    for (int mf = 0; mf < 8; ++mf) {                                                          \
      const int rr = arow + mf * 16 + r15;                                                    \
      af[mf] = *(const bf16x8*)&LA[DD][rr * 32 + ((g ^ ((rr >> 1) & 3)) << 3)];               \
    }                                                                                         \
    {                                                                                         \
      const int rb0 = wn * 64 + r15, rb1 = wn * 64 + 16 + r15;                                \
      const int rb2 = wn * 64 + 32 + r15, rb3 = wn * 64 + 48 + r15;                           \
      b0 = *(const bf16x8*)&LB[DD][rb0 * 32 + ((g ^ ((rb0 >> 1) & 3)) << 3)];                 \
      b1 = *(const bf16x8*)&LB[DD][rb1 * 32 + ((g ^ ((rb1 >> 1) & 3)) << 3)];                 \
      b2 = *(const bf16x8*)&LB[DD][rb2 * 32 + ((g ^ ((rb2 >> 1) & 3)) << 3)];                 \
      b3 = *(const bf16x8*)&LB[DD][rb3 * 32 + ((g ^ ((rb3 >> 1) & 3)) << 3)];                 \
    }                                                                                         \
    __builtin_amdgcn_s_barrier();                                                             \
    __builtin_amdgcn_s_setprio(1);                                                            \
    _Pragma("unroll")                                                                         \
    for (int mf = 0; mf < 8; ++mf) {                                                          \
      acc[mf][0] = MFMA16(af[mf], b0, acc[mf][0]);                                            \
      acc[mf][1] = MFMA16(af[mf], b1, acc[mf][1]);                                            \
    }                                                                                         \
    __builtin_amdgcn_s_setprio(0);                                                            \
    /* phase 1: stage t+2 + MFMA nf2,3 */                                                     \
    stA(DD, t2); stB(DD, t2);                                                                 \
    asm volatile("s_waitcnt vmcnt(4)" ::: "memory");                                          \
    __builtin_amdgcn_s_barrier();                                                             \
    __builtin_amdgcn_s_setprio(1);                                                            \
    _Pragma("unroll")                                                                         \
    for (int mf = 0; mf < 8; ++mf) {                                                          \
      acc[mf][2] = MFMA16(af[mf], b2, acc[mf][2]);                                            \
      acc[mf][3] = MFMA16(af[mf], b3, acc[mf][3]);                                            \
    }                                                                                         \
    __builtin_amdgcn_s_setprio(0);                                                            \
  }

  for (int tt = 0; tt < nt; tt += 2) {
    GEMM_T32(0, tt);
    GEMM_T32(1, tt + 1);
  }
#undef GEMM_T32

  #pragma unroll
  for (int mf = 0; mf < 8; ++mf)
    #pragma unroll
    for (int nf = 0; nf < 4; ++nf) {
      const size_t col = n0 + wn * 64 + nf * 16 + r15;
      #pragma unroll
      for (int rr = 0; rr < 4; ++rr) {
        const size_t row = m0 + wm * 128 + mf * 16 + g * 4 + rr;
        const size_t idx = row * (size_t)N + col;
        const float v = acc[mf][nf][rr];
        if (MODE == 0) Cf[idx] = v;
        else if (MODE == 1) Cb[idx] = (bf16)v;
        else if (MODE == 2) Cf[idx] = v + res[idx];
        else { const float s = v + res[idx]; Cf[idx] = s; Cb[idx] = (bf16)s; }
      }
    }
}

// ======= fused GEGLU GEMM: tile 256x128, BK=32 2-phase, 64KB LDS -> 2 blocks/CU =======
__global__ __launch_bounds__(512, 4) void k_geglu2(const bf16* __restrict__ A, const bf16* __restrict__ BT,
                                                   bf16* __restrict__ G, int N, int K,
                                                   int XGM, int BYG, int BXG) {
  __shared__ bf16 LA[2][256 * 32];   // 16KB each
  __shared__ bf16 LBv[2][128 * 32];  // 8KB each
  __shared__ bf16 LBg[2][128 * 32];
  int by, bx;
  xcd_map(blockIdx.x, XGM, BYG, BXG, by, bx);
  const size_t m0 = (size_t)by * 256, n0 = (size_t)bx * 128;
  const int t = threadIdx.x;
  const int w = t >> 6, lane = t & 63;
  const int wm = w >> 2, wn = w & 3;
  const int g = lane >> 4, r15 = lane & 15;
  const int nt = K >> 5;
  const int sr0 = t >> 2, ss0 = t & 3;
  const int sr1 = (t + 512) >> 2, ss1 = (t + 512) & 3;
  const int sc0 = ((ss0 ^ ((sr0 >> 1) & 3)) << 3);
  const int sc1 = ((ss1 ^ ((sr1 >> 1) & 3)) << 3);
  f32x4 av[8][2] = {}, ag[8][2] = {};

  auto stA = [&](int db, int st) {
    const bf16* src = A + m0 * K + (size_t)st * 32;
    gload16(src + (size_t)sr0 * K + sc0, &LA[db][t * 8]);
    gload16(src + (size_t)sr1 * K + sc1, &LA[db][(t + 512) * 8]);
  };
  auto stBv = [&](int db, int st) {
    const bf16* src = BT + n0 * K + (size_t)st * 32;
    gload16(src + (size_t)sr0 * K + sc0, &LBv[db][t * 8]);
  };
  auto stBg = [&](int db, int st) {
    const bf16* src = BT + ((size_t)N + n0) * K + (size_t)st * 32;
    gload16(src + (size_t)sr0 * K + sc0, &LBg[db][t * 8]);
  };

  // prologue: T0 + T1 = 8 loads/thread
  stA(0, 0); stBv(0, 0); stBg(0, 0); stA(1, 1); stBv(1, 1); stBg(1, 1);
  asm volatile("s_waitcnt vmcnt(4)" ::: "memory");
  __builtin_amdgcn_s_barrier();

  const int arow = wm * 128;

#define GEGLU_T32(DD, TC)                                                                     \
  {                                                                                           \
    const int t2 = ((TC) + 2 < nt) ? (TC) + 2 : nt - 1;                                       \
    bf16x8 af[8], b0, b1, b2, b3;                                                             \
    /* phase 0: reads + MFMA val */                                                           \
    _Pragma("unroll")                                                                         \
    for (int mf = 0; mf < 8; ++mf) {                                                          \
      const int rr = arow + mf * 16 + r15;                                                    \
      af[mf] = *(const bf16x8*)&LA[DD][rr * 32 + ((g ^ ((rr >> 1) & 3)) << 3)];               \
    }                                                                                         \
    {                                                                                         \
      const int rb0 = wn * 32 + r15, rb1 = wn * 32 + 16 + r15;                                \
      b0 = *(const bf16x8*)&LBv[DD][rb0 * 32 + ((g ^ ((rb0 >> 1) & 3)) << 3)];                \
      b1 = *(const bf16x8*)&LBv[DD][rb1 * 32 + ((g ^ ((rb1 >> 1) & 3)) << 3)];                \
      b2 = *(const bf16x8*)&LBg[DD][rb0 * 32 + ((g ^ ((rb0 >> 1) & 3)) << 3)];                \
      b3 = *(const bf16x8*)&LBg[DD][rb1 * 32 + ((g ^ ((rb1 >> 1) & 3)) << 3)];                \
    }                                                                                         \
    __builtin_amdgcn_s_barrier();                                                             \
    __builtin_amdgcn_s_setprio(1);                                                            \
    _Pragma("unroll")                                                                         \
    for (int mf = 0; mf < 8; ++mf) {                                                          \
      av[mf][0] = MFMA16(af[mf], b0, av[mf][0]);                                              \
      av[mf][1] = MFMA16(af[mf], b1, av[mf][1]);                                              \
    }                                                                                         \
    __builtin_amdgcn_s_setprio(0);                                                            \
    /* phase 1: stage t+2 + MFMA gate */                                                      \
    stA(DD, t2); stBv(DD, t2); stBg(DD, t2);                                                  \
    asm volatile("s_waitcnt vmcnt(4)" ::: "memory");                                          \
    __builtin_amdgcn_s_barrier();                                                             \
    __builtin_amdgcn_s_setprio(1);                                                            \
    _Pragma("unroll")                                                                         \
    for (int mf = 0; mf < 8; ++mf) {                                                          \
      ag[mf][0] = MFMA16(af[mf], b2, ag[mf][0]);                                              \
      ag[mf][1] = MFMA16(af[mf], b3, ag[mf][1]);                                              \
    }                                                                                         \
    __builtin_amdgcn_s_setprio(0);                                                            \
  }

  for (int tt = 0; tt < nt; tt += 2) {
    GEGLU_T32(0, tt);
    GEGLU_T32(1, tt + 1);
  }
#undef GEGLU_T32

  #pragma unroll
  for (int mf = 0; mf < 8; ++mf)
    #pragma unroll
    for (int nf = 0; nf < 2; ++nf) {
      const size_t col = n0 + wn * 32 + nf * 16 + r15;
      #pragma unroll
      for (int rr = 0; rr < 4; ++rr) {
        const size_t row = m0 + wm * 128 + mf * 16 + g * 4 + rr;
        const float val = av[mf][nf][rr], gt = ag[mf][nf][rr];
        const float z = 1.595769122f * gt + 0.0713548162f * gt * gt * gt;
        const float gel = gt / (1.f + __expf(-z));
        G[row * (size_t)N + col] = (bf16)(val * gel);
      }
    }
}

// ---------------- 128x128 GEMM (m97 structure) for M=256 cases ----------------
template <int MODE>
__global__ __launch_bounds__(256) void k_gemm128(const bf16* __restrict__ A, const bf16* __restrict__ BT,
                                                 float* __restrict__ Cf, bf16* __restrict__ Cb,
                                                 int M, int N, int K) {
  __shared__ bf16 As[128 * 32];
  __shared__ bf16 Bs[128 * 32];
  const int t = threadIdx.x;
  const int lane = t & 63, w = t >> 6;
  const int wr = w >> 1, wc = w & 1;
  const int g = lane >> 4, r15 = lane & 15;
  const size_t m0 = (size_t)blockIdx.y * 128, n0 = (size_t)blockIdx.x * 128;
  f32x4 acc[4][4] = {};
  const int c0 = t, c1 = t + 256;
  const int ar0 = c0 >> 2, as0 = c0 & 3, ar1 = c1 >> 2, as1 = c1 & 3;
  const bf16* Ab = A + m0 * K;
  const bf16* Bb = BT + n0 * K;
  for (int k0 = 0; k0 < K; k0 += 32) {
    __syncthreads();
    gload16(Ab + (size_t)ar0 * K + k0 + ((as0 ^ (ar0 & 3)) << 3), &As[c0 * 8]);
    gload16(Ab + (size_t)ar1 * K + k0 + ((as1 ^ (ar1 & 3)) << 3), &As[c1 * 8]);
    gload16(Bb + (size_t)ar0 * K + k0 + ((as0 ^ (ar0 & 3)) << 3), &Bs[c0 * 8]);
    gload16(Bb + (size_t)ar1 * K + k0 + ((as1 ^ (ar1 & 3)) << 3), &Bs[c1 * 8]);
    __syncthreads();
    bf16x8 af[4], bfr[4];
    #pragma unroll
    for (int mi = 0; mi < 4; mi++) {
      int row = wr * 64 + mi * 16 + r15;
      af[mi] = *(const bf16x8*)&As[row * 32 + ((g ^ (row & 3)) << 3)];
    }
    #pragma unroll
    for (int ni = 0; ni < 4; ni++) {
      int row = wc * 64 + ni * 16 + r15;
      bfr[ni] = *(const bf16x8*)&Bs[row * 32 + ((g ^ (row & 3)) << 3)];
    }
    #pragma unroll
    for (int mi = 0; mi < 4; mi++)
      #pragma unroll
      for (int ni = 0; ni < 4; ni++)
        acc[mi][ni] = MFMA16(af[mi], bfr[ni], acc[mi][ni]);
  }
  #pragma unroll
  for (int mi = 0; mi < 4; mi++)
    #pragma unroll
    for (int ni = 0; ni < 4; ni++) {
      size_t col = n0 + wc * 64 + ni * 16 + r15;
      #pragma unroll
      for (int rr = 0; rr < 4; rr++) {
        size_t row = m0 + wr * 64 + mi * 16 + g * 4 + rr;
        size_t idx = row * (size_t)N + col;
        float v = acc[mi][ni][rr];
        if (MODE == 0) Cf[idx] = v;
        else Cb[idx] = (bf16)v;
      }
    }
}

// ---------------- flash attention (round-9 structure + exact defer-max; q pre-scaled) ------------
// grid (S/64, H), 4 waves x 16 q-rows, KVBLK=64, 40KB LDS.
__global__ __launch_bounds__(256) void k_attn(const bf16* __restrict__ Q, const bf16* __restrict__ Kb,
                                              const bf16* __restrict__ VT, bf16* __restrict__ O,
                                              int Skv) {
  __shared__ bf16 Kt[64 * 128];   // [key][d], 16 slots/row, slot ^= (key&15)
  __shared__ bf16 Vt[128 * 64];   // [d][key], 8 slots/row, slot ^= (d&7)
  __shared__ bf16 Pt[4][16 * 64]; // per-wave P, 8 slots/row, slot ^= (q&7)
  const int h = blockIdx.y;
  const int t = threadIdx.x, w = t >> 6, lane = t & 63;
  const int g = lane >> 4, r15 = lane & 15;
  const int q0 = blockIdx.x * 64 + w * 16;
  bf16x8 qf[4];
  #pragma unroll
  for (int c = 0; c < 4; c++)
    qf[c] = *(const bf16x8*)(Q + (size_t)(q0 + r15) * D + h * 128 + c * 32 + g * 8);
  f32x4 o[8] = {};
  float m_[4] = { -1e30f, -1e30f, -1e30f, -1e30f };
  float l_[4] = { 0.f, 0.f, 0.f, 0.f };
  for (int kt = 0; kt < Skv; kt += 64) {
    __syncthreads();
    #pragma unroll
    for (int cc = 0; cc < 4; cc++) {
      int c = t + cc * 256;
      int kr = c >> 4, ks = c & 15;
      gload16(Kb + (size_t)(kt + kr) * D + h * 128 + ((ks ^ (kr & 15)) << 3), &Kt[c * 8]);
      int vr = c >> 3, vs = c & 7;
      gload16(VT + (size_t)(h * 128 + vr) * Skv + kt + ((vs ^ (vr & 7)) << 3), &Vt[c * 8]);
    }
    __syncthreads();
    f32x4 s[4] = {};
    __builtin_amdgcn_s_setprio(1);
    #pragma unroll
    for (int c = 0; c < 4; c++) {
      #pragma unroll
      for (int j = 0; j < 4; j++) {
        const int row = j * 16 + r15;
        bf16x8 kf = *(const bf16x8*)&Kt[row * 128 + (((4 * c + g) ^ (row & 15)) << 3)];
        s[j] = MFMA16(qf[c], kf, s[j]);
      }
    }
    __builtin_amdgcn_s_setprio(0);
    float sv[4][4], mxs[4];
    bool grow = false;
    #pragma unroll
    for (int rr = 0; rr < 4; rr++) {
      sv[rr][0] = s[0][rr]; sv[rr][1] = s[1][rr]; sv[rr][2] = s[2][rr]; sv[rr][3] = s[3][rr];
      float mx = fmaxf(fmaxf(sv[rr][0], sv[rr][1]), fmaxf(sv[rr][2], sv[rr][3]));
      #pragma unroll
      for (int off = 1; off < 16; off <<= 1) mx = fmaxf(mx, __shfl_xor(mx, off, 16));
      mxs[rr] = mx;
      grow = grow || (mx > m_[rr]);
    }
    if (__any(grow ? 1 : 0)) {  // EXACT: when no row max grows, rescale factor is exp(0)=1
      float al[4];
      #pragma unroll
      for (int rr = 0; rr < 4; rr++) {
        float mn = fmaxf(m_[rr], mxs[rr]);
        al[rr] = __expf(m_[rr] - mn);
        l_[rr] *= al[rr];
        m_[rr] = mn;
      }
      #pragma unroll
      for (int d = 0; d < 8; d++)
        #pragma unroll
        for (int rr = 0; rr < 4; rr++) o[d][rr] *= al[rr];
    }
    #pragma unroll
    for (int rr = 0; rr < 4; rr++) {
      float p0 = __expf(sv[rr][0] - m_[rr]), p1 = __expf(sv[rr][1] - m_[rr]);
      float p2 = __expf(sv[rr][2] - m_[rr]), p3 = __expf(sv[rr][3] - m_[rr]);
      float sm = p0 + p1 + p2 + p3;
      #pragma unroll
      for (int off = 1; off < 16; off <<= 1) sm += __shfl_xor(sm, off, 16);
      l_[rr] += sm;
      const int prow = g * 4 + rr;
      const int sbase = prow * 64, sx = prow & 7, e = r15 & 7, hi = r15 >> 3;
      Pt[w][sbase + (((0 + hi) ^ sx) << 3) + e] = (bf16)p0;
      Pt[w][sbase + (((2 + hi) ^ sx) << 3) + e] = (bf16)p1;
      Pt[w][sbase + (((4 + hi) ^ sx) << 3) + e] = (bf16)p2;
      Pt[w][sbase + (((6 + hi) ^ sx) << 3) + e] = (bf16)p3;
    }
    bf16x8 pa[2];
    #pragma unroll
    for (int kk = 0; kk < 2; kk++)
      pa[kk] = *(const bf16x8*)&Pt[w][r15 * 64 + (((kk * 4 + g) ^ (r15 & 7)) << 3)];
    __builtin_amdgcn_s_setprio(1);
    #pragma unroll
    for (int d = 0; d < 8; d++) {
      const int vrow = d * 16 + r15;
      #pragma unroll
      for (int kk = 0; kk < 2; kk++) {
        bf16x8 vbf = *(const bf16x8*)&Vt[vrow * 64 + (((kk * 4 + g) ^ (vrow & 7)) << 3)];
        o[d] = MFMA16(pa[kk], vbf, o[d]);
      }
    }
    __builtin_amdgcn_s_setprio(0);
  }
  #pragma unroll
  for (int rr = 0; rr < 4; rr++) {
    float inv = 1.f / l_[rr];
    #pragma unroll
    for (int d = 0; d < 8; d++)
      O[(size_t)(q0 + g * 4 + rr) * D + h * 128 + d * 16 + r15] = (bf16)(o[d][rr] * inv);
  }
}

extern "C" void kernel_launch(void* const* d_in, const int* in_sizes, int n_in,
                              void* d_out, int out_size, void* d_ws, size_t ws_size,
                              hipStream_t stream) {
  (void)in_sizes; (void)n_in; (void)out_size; (void)ws_size;
  const float* video = (const float*)d_in[0];
  const float* text  = (const float*)d_in[1];
  const float* wq    = (const float*)d_in[2];
  const float* wk    = (const float*)d_in[3];
  const float* wv    = (const float*)d_in[4];
  const float* wo    = (const float*)d_in[5];
  const float* qnw   = (const float*)d_in[6];
  const float* knw   = (const float*)d_in[7];
  const float* cwq   = (const float*)d_in[8];
  const float* cwk   = (const float*)d_in[9];
  const float* cwv   = (const float*)d_in[10];
  const float* cwo   = (const float*)d_in[11];
  const float* cqnw  = (const float*)d_in[12];
  const float* cknw  = (const float*)d_in[13];
  const float* ffp   = (const float*)d_in[14];
  const float* ffd   = (const float*)d_in[15];
  float* out = (float*)d_out;
  const float SCQ = 0.08838834764831845f;  // 1/sqrt(128), folded into q

  char* slab = (char*)d_ws;
  const size_t MB = 1024 * 1024;
  bf16*  wbuf   = (bf16*)slab;
  bf16*  vt     = (bf16*)(slab + 96 * MB);
  bf16*  preqkv = (bf16*)(slab + 128 * MB);
  bf16*  Hval   = (bf16*)(slab + 268 * MB);
  char* p = slab + 402 * MB;
  auto take = [&](size_t bytes) { char* r = p; p += (bytes + 255) & ~(size_t)255; return r; };
  bf16* xb   = (bf16*)take((size_t)S * D * 2);
  bf16* qb   = (bf16*)take((size_t)S * D * 2);
  bf16* kb   = (bf16*)take((size_t)S * D * 2);
  bf16* ab   = (bf16*)take((size_t)S * D * 2);
  float* h1  = (float*)take((size_t)S * D * 4);
  bf16* tbuf = (bf16*)take((size_t)T * D * 2);
  bf16* ckb  = (bf16*)take((size_t)T * D * 2);
  bf16* cvb  = (bf16*)take((size_t)T * D * 2);
  bf16* cvt_ = (bf16*)take((size_t)T * D * 2);
  float* h2  = out;

  dim3 b256(256), b512(512), btc(64, 4), btb(32, 8);
  const int GRID_DD = 256, GRID_GG = 2048, GRID_QKV = 768;

  // ---- self-attention ----
  k_cvt<<<(S * D) / 1024, b256, 0, stream>>>(video, xb, S * D);
  k_tc<<<dim3(D / 64, D / 64), btc, 0, stream>>>(wq, wbuf, D, D, D);
  k_tc<<<dim3(D / 64, D / 64), btc, 0, stream>>>(wk, wbuf + (size_t)D * D, D, D, D);
  k_tc<<<dim3(D / 64, D / 64), btc, 0, stream>>>(wv, wbuf + 2 * (size_t)D * D, D, D, D);
  k_gemm2<1><<<GRID_QKV, b512, 0, stream>>>(xb, wbuf, nullptr, preqkv, nullptr, S, 3 * D, D, 2, 8, 12);
  k_rms<<<S, b256, 0, stream>>>(preqkv, qnw, qb, 3 * D, SCQ);
  k_rms<<<S, b256, 0, stream>>>(preqkv + D, knw, kb, 3 * D, 1.f);
  k_tb<<<dim3(D / 32, S / 32), btb, 0, stream>>>(preqkv + 2 * D, vt, S, D, 3 * D);
  k_attn<<<dim3(S / 64, H), b256, 0, stream>>>(qb, kb, vt, ab, S);
  k_tc<<<dim3(D / 64, D / 64), btc, 0, stream>>>(wo, wbuf, D, D, D);
  k_gemm2<3><<<GRID_DD, b512, 0, stream>>>(ab, wbuf, h1, xb, video, S, D, D, 2, 8, 4);

  // ---- cross-attention ----
  k_tc<<<dim3(D / 64, D / 64), btc, 0, stream>>>(cwq, wbuf, D, D, D);
  k_gemm2<1><<<GRID_DD, b512, 0, stream>>>(xb, wbuf, nullptr, preqkv, nullptr, S, D, D, 2, 8, 4);
  k_rms<<<S, b256, 0, stream>>>(preqkv, cqnw, qb, D, SCQ);
  k_cvt<<<(T * D) / 1024, b256, 0, stream>>>(text, tbuf, T * D);
  k_tc<<<dim3(D / 64, D / 64), btc, 0, stream>>>(cwk, wbuf, D, D, D);
  k_gemm128<1><<<dim3(D / 128, T / 128), b256, 0, stream>>>(tbuf, wbuf, nullptr, preqkv, T, D, D);
  k_rms<<<T, b256, 0, stream>>>(preqkv, cknw, ckb, D, 1.f);
  k_tc<<<dim3(D / 64, D / 64), btc, 0, stream>>>(cwv, wbuf, D, D, D);
  k_gemm128<1><<<dim3(D / 128, T / 128), b256, 0, stream>>>(tbuf, wbuf, nullptr, cvb, T, D, D);
  k_tb<<<dim3(D / 32, T / 32), btb, 0, stream>>>(cvb, cvt_, T, D, D);
  k_attn<<<dim3(S / 64, H), b256, 0, stream>>>(qb, ckb, cvt_, ab, T);
  k_tc<<<dim3(D / 64, D / 64), btc, 0, stream>>>(cwo, wbuf, D, D, D);
  k_gemm2<3><<<GRID_DD, b512, 0, stream>>>(ab, wbuf, h2, xb, h1, S, D, D, 2, 8, 4);

  // ---- GEGLU FFN (fused val+gate) ----
  k_tc<<<dim3((2 * F) / 64, D / 64), btc, 0, stream>>>(ffp, wbuf, D, 2 * F, 2 * F);
  k_geglu2<<<GRID_GG, b512, 0, stream>>>(xb, wbuf, Hval, F, D, 2, 8, 32);
  k_tc<<<dim3(D / 64, F / 64), btc, 0, stream>>>(ffd, wbuf, F, D, D);
  k_gemm2<2><<<GRID_DD, b512, 0, stream>>>(Hval, wbuf, out, nullptr, h2, S, D, F, 2, 8, 4);
}

// Round 14
// 3653.530 us; speedup vs baseline: 8.3618x; 8.3618x over previous
//
#include <hip/hip_runtime.h>
#include <cstdint>
#include <cstddef>

typedef __bf16 bf16;
typedef __bf16 bf16x8 __attribute__((ext_vector_type(8)));
typedef __bf16 bf16x4 __attribute__((ext_vector_type(4)));
typedef float f32x4 __attribute__((ext_vector_type(4)));

static constexpr int D = 4096;
static constexpr int S = 4096;
static constexpr int T = 256;
static constexpr int H = 32;
static constexpr int F = 16384;

__device__ __forceinline__ void gload16(const void* g, void* l) {
  __builtin_amdgcn_global_load_lds((const __attribute__((address_space(1))) void*)g,
                                   (__attribute__((address_space(3))) void*)l, 16, 0, 0);
}

#define MFMA16(a, b, c) __builtin_amdgcn_mfma_f32_16x16x32_bf16((a), (b), (c), 0, 0, 0)

// ---------------- elementwise f32 -> bf16 ----------------
__global__ __launch_bounds__(256) void k_cvt(const float* __restrict__ in, bf16* __restrict__ out, int n) {
  int i = (blockIdx.x * 256 + threadIdx.x) * 4;
  if (i >= n) return;
  float4 v = *(const float4*)(in + i);
  bf16x4 o = { (bf16)v.x, (bf16)v.y, (bf16)v.z, (bf16)v.w };
  *(bf16x4*)(out + i) = o;
}

// ---------------- transpose+cvt: f32 [R][C] (row stride ldin) -> bf16 [C][R], 64x64 tiles --------
__global__ __launch_bounds__(256) void k_tc(const float* __restrict__ in, bf16* __restrict__ out,
                                            int R, int C, int ldin) {
  __shared__ float tile[64][65];
  const int c0 = blockIdx.x * 64, r0 = blockIdx.y * 64;
  const int x = threadIdx.x, y = threadIdx.y;  // block (64,4)
  #pragma unroll
  for (int i = 0; i < 16; i++) {
    const int yy = y + 4 * i;
    tile[yy][x] = in[(size_t)(r0 + yy) * ldin + c0 + x];
  }
  __syncthreads();
  #pragma unroll
  for (int i = 0; i < 16; i++) {
    const int yy = y + 4 * i;
    out[(size_t)(c0 + yy) * R + r0 + x] = (bf16)tile[x][yy];
  }
}

// ---------------- transpose bf16 [R][C] (row stride ldin) -> [C][R] ----------------
__global__ __launch_bounds__(256) void k_tb(const bf16* __restrict__ in, bf16* __restrict__ out,
                                            int R, int C, int ldin) {
  __shared__ bf16 tile[32][33];
  int c0 = blockIdx.x * 32, r0 = blockIdx.y * 32;
  int x = threadIdx.x, y = threadIdx.y;
  #pragma unroll
  for (int yy = y; yy < 32; yy += 8)
    tile[yy][x] = in[(size_t)(r0 + yy) * ldin + c0 + x];
  __syncthreads();
  #pragma unroll
  for (int yy = y; yy < 32; yy += 8)
    out[(size_t)(c0 + yy) * R + r0 + x] = tile[x][yy];
}

// ---------------- rmsnorm over 4096, bf16 in (row stride ldin) -> bf16 out, scaled ---------------
__global__ __launch_bounds__(256) void k_rms(const bf16* __restrict__ in, const float* __restrict__ w,
                                             bf16* __restrict__ out, int ldin, float sc) {
  const int row = blockIdx.x, t = threadIdx.x;
  const bf16* x = in + (size_t)row * ldin;
  float xv[16];
  float ss = 0.f;
  #pragma unroll
  for (int i = 0; i < 2; i++) {
    bf16x8 b = *(const bf16x8*)(x + t * 8 + i * 2048);
    #pragma unroll
    for (int j = 0; j < 8; j++) { xv[i * 8 + j] = (float)b[j]; ss += xv[i * 8 + j] * xv[i * 8 + j]; }
  }
  #pragma unroll
  for (int off = 1; off < 64; off <<= 1) ss += __shfl_xor(ss, off, 64);
  __shared__ float red[4];
  if ((t & 63) == 0) red[t >> 6] = ss;
  __syncthreads();
  float rms = rsqrtf((red[0] + red[1] + red[2] + red[3]) * (1.f / 4096.f) + 1e-6f) * sc;
  #pragma unroll
  for (int i = 0; i < 2; i++) {
    float4 w0 = *(const float4*)(w + t * 8 + i * 2048);
    float4 w1 = *(const float4*)(w + t * 8 + i * 2048 + 4);
    bf16x8 ov;
    ov[0] = (bf16)(xv[i * 8 + 0] * rms * w0.x); ov[1] = (bf16)(xv[i * 8 + 1] * rms * w0.y);
    ov[2] = (bf16)(xv[i * 8 + 2] * rms * w0.z); ov[3] = (bf16)(xv[i * 8 + 3] * rms * w0.w);
    ov[4] = (bf16)(xv[i * 8 + 4] * rms * w1.x); ov[5] = (bf16)(xv[i * 8 + 5] * rms * w1.y);
    ov[6] = (bf16)(xv[i * 8 + 6] * rms * w1.z); ov[7] = (bf16)(xv[i * 8 + 7] * rms * w1.w);
    *(bf16x8*)(out + (size_t)row * 4096 + t * 8 + i * 2048) = ov;
  }
}

// supertile XCD mapping (bijective): by = (xcd%XGM)*BYG + oidx%BYG ; bx = (xcd/XGM)*BXG + oidx/BYG
__device__ __forceinline__ void xcd_map(int orig, int XGM, int BYG, int BXG, int& by, int& bx) {
  const int xcd = orig & 7, oidx = orig >> 3;
  by = (xcd % XGM) * BYG + oidx % BYG;
  bx = (xcd / XGM) * BXG + oidx / BYG;
}

// ================= 256x256 counted-vmcnt GEMM, 4 phases, tile-loop unrolled x2 (BEST) ============
// MODE 0: f32 out; 1: bf16 out; 2: f32 = v+res; 3: f32 = v+res AND bf16 dual write
template <int MODE>
__global__ __launch_bounds__(512, 2) void k_gemm2(const bf16* __restrict__ A, const bf16* __restrict__ BT,
                                                  float* __restrict__ Cf, bf16* __restrict__ Cb,
                                                  const float* __restrict__ res,
                                                  int M, int N, int K, int XGM, int BYG, int BXG) {
  __shared__ bf16 LA[2][2][256 * 32];  // [dbuf][kh][row*32+col]
  __shared__ bf16 LB[2][2][256 * 32];
  int by, bx;
  xcd_map(blockIdx.x, XGM, BYG, BXG, by, bx);
  const size_t m0 = (size_t)by * 256, n0 = (size_t)bx * 256;
  const int t = threadIdx.x;
  const int w = t >> 6, lane = t & 63;
  const int wm = w >> 2, wn = w & 3;
  const int g = lane >> 4, r15 = lane & 15;
  const int nt = K >> 6;
  const int sr0 = t >> 2, ss0 = t & 3;
  const int sr1 = (t + 512) >> 2, ss1 = (t + 512) & 3;
  const int sc0 = ((ss0 ^ ((sr0 >> 1) & 3)) << 3);
  const int sc1 = ((ss1 ^ ((sr1 >> 1) & 3)) << 3);
  f32x4 acc[8][4] = {};

  auto stA = [&](int db, int kh, int st) {
    const bf16* src = A + m0 * K + (size_t)st * 64 + kh * 32;
    gload16(src + (size_t)sr0 * K + sc0, &LA[db][kh][t * 8]);
    gload16(src + (size_t)sr1 * K + sc1, &LA[db][kh][(t + 512) * 8]);
  };
  auto stB = [&](int db, int kh, int st) {
    const bf16* src = BT + n0 * K + (size_t)st * 64 + kh * 32;
    gload16(src + (size_t)sr0 * K + sc0, &LB[db][kh][t * 8]);
    gload16(src + (size_t)sr1 * K + sc1, &LB[db][kh][(t + 512) * 8]);
  };

  stA(0, 0, 0); stB(0, 0, 0); stA(0, 1, 0); stB(0, 1, 0);
  stA(1, 0, 1); stB(1, 0, 1); stA(1, 1, 1);
  asm volatile("s_waitcnt vmcnt(10)" ::: "memory");
  __builtin_amdgcn_s_barrier();

  const int arow = wm * 128;

#define GEMM_TILE(DD, TC)                                                                     \
  {                                                                                           \
    const int t1 = ((TC) + 1 < nt) ? (TC) + 1 : nt - 1;                                       \
    const int t2 = ((TC) + 2 < nt) ? (TC) + 2 : nt - 1;                                       \
    bf16x8 af[8], b0, b1;                                                                     \
    stB((DD) ^ 1, 1, t1);                                                                     \
    _Pragma("unroll")                                                                         \
    for (int mf = 0; mf < 8; ++mf) {                                                          \
      const int rr = arow + mf * 16 + r15;                                                    \
      af[mf] = *(const bf16x8*)&LA[DD][0][rr * 32 + ((g ^ ((rr >> 1) & 3)) << 3)];            \
    }                                                                                         \
    {                                                                                         \
      const int rb0 = wn * 64 + r15, rb1 = wn * 64 + 16 + r15;                                \
      b0 = *(const bf16x8*)&LB[DD][0][rb0 * 32 + ((g ^ ((rb0 >> 1) & 3)) << 3)];              \
      b1 = *(const bf16x8*)&LB[DD][0][rb1 * 32 + ((g ^ ((rb1 >> 1) & 3)) << 3)];              \
    }                                                                                         \
    __builtin_amdgcn_s_barrier();                                                             \
    __builtin_amdgcn_s_setprio(1);                                                            \
    _Pragma("unroll")                                                                         \
    for (int mf = 0; mf < 8; ++mf) {                                                          \
      acc[mf][0] = MFMA16(af[mf], b0, acc[mf][0]);                                            \
      acc[mf][1] = MFMA16(af[mf], b1, acc[mf][1]);                                            \
    }                                                                                         \
    __builtin_amdgcn_s_setprio(0);                                                            \
    stA(DD, 0, t2);                                                                           \
    {                                                                                         \
      const int rb0 = wn * 64 + 32 + r15, rb1 = wn * 64 + 48 + r15;                           \
      b0 = *(const bf16x8*)&LB[DD][0][rb0 * 32 + ((g ^ ((rb0 >> 1) & 3)) << 3)];              \
      b1 = *(const bf16x8*)&LB[DD][0][rb1 * 32 + ((g ^ ((rb1 >> 1) & 3)) << 3)];              \
    }                                                                                         \
    asm volatile("s_waitcnt vmcnt(10)" ::: "memory");                                         \
    __builtin_amdgcn_s_barrier();                                                             \
    __builtin_amdgcn_s_setprio(1);                                                            \
    _Pragma("unroll")                                                                         \
    for (int mf = 0; mf < 8; ++mf) {                                                          \
      acc[mf][2] = MFMA16(af[mf], b0, acc[mf][2]);                                            \
      acc[mf][3] = MFMA16(af[mf], b1, acc[mf][3]);                                            \
    }                                                                                         \
    __builtin_amdgcn_s_setprio(0);                                                            \
    stB(DD, 0, t2);                                                                           \
    _Pragma("unroll")                                                                         \
    for (int mf = 0; mf < 8; ++mf) {                                                          \
      const int rr = arow + mf * 16 + r15;                                                    \
      af[mf] = *(const bf16x8*)&LA[DD][1][rr * 32 + ((g ^ ((rr >> 1) & 3)) << 3)];            \
    }                                                                                         \
    {                                                                                         \
      const int rb0 = wn * 64 + r15, rb1 = wn * 64 + 16 + r15;                                \
      b0 = *(const bf16x8*)&LB[DD][1][rb0 * 32 + ((g ^ ((rb0 >> 1) & 3)) << 3)];              \
      b1 = *(const bf16x8*)&LB[DD][1][rb1 * 32 + ((g ^ ((rb1 >> 1) & 3)) << 3)];              \
    }                                                                                         \
    __builtin_amdgcn_s_barrier();                                                             \
    __builtin_amdgcn_s_setprio(1);                                                            \
    _Pragma("unroll")                                                                         \
    for (int mf = 0; mf < 8; ++mf) {                                                          \
      acc[mf][0] = MFMA16(af[mf], b0, acc[mf][0]);                                            \
      acc[mf][1] = MFMA16(af[mf], b1, acc[mf][1]);                                            \
    }                                                                                         \
    __builtin_amdgcn_s_setprio(0);                                                            \
    stA(DD, 1, t2);                                                                           \
    {                                                                                         \
      const int rb0 = wn * 64 + 32 + r15, rb1 = wn * 64 + 48 + r15;                           \
      b0 = *(const bf16x8*)&LB[DD][1][rb0 * 32 + ((g ^ ((rb0 >> 1) & 3)) << 3)];              \
      b1 = *(const bf16x8*)&LB[DD][1][rb1 * 32 + ((g ^ ((rb1 >> 1) & 3)) << 3)];              \
    }                                                                                         \
    asm volatile("s_waitcnt vmcnt(10)" ::: "memory");                                         \
    __builtin_amdgcn_s_barrier();                                                             \
    __builtin_amdgcn_s_setprio(1);                                                            \
    _Pragma("unroll")                                                                         \
    for (int mf = 0; mf < 8; ++mf) {                                                          \
      acc[mf][2] = MFMA16(af[mf], b0, acc[mf][2]);                                            \
      acc[mf][3] = MFMA16(af[mf], b1, acc[mf][3]);                                            \
    }                                                                                         \
    __builtin_amdgcn_s_setprio(0);                                                            \
  }

  for (int tt = 0; tt < nt; tt += 2) {
    GEMM_TILE(0, tt);
    GEMM_TILE(1, tt + 1);
  }
#undef GEMM_TILE

  #pragma unroll
  for (int mf = 0; mf < 8; ++mf)
    #pragma unroll
    for (int nf = 0; nf < 4; ++nf) {
      const size_t col = n0 + wn * 64 + nf * 16 + r15;
      #pragma unroll
      for (int rr = 0; rr < 4; ++rr) {
        const size_t row = m0 + wm * 128 + mf * 16 + g * 4 + rr;
        const size_t idx = row * (size_t)N + col;
        const float v = acc[mf][nf][rr];
        if (MODE == 0) Cf[idx] = v;
        else if (MODE == 1) Cb[idx] = (bf16)v;
        else if (MODE == 2) Cf[idx] = v + res[idx];
        else { const float s = v + res[idx]; Cf[idx] = s; Cb[idx] = (bf16)s; }
      }
    }
}

// ================= fused GEGLU GEMM: tile 256x128, 4 phases (BEST) ===============================
__global__ __launch_bounds__(512, 2) void k_geglu2(const bf16* __restrict__ A, const bf16* __restrict__ BT,
                                                   bf16* __restrict__ G, int N, int K,
                                                   int XGM, int BYG, int BXG) {
  __shared__ bf16 LA[2][2][256 * 32];
  __shared__ bf16 LBv[2][2][128 * 32];
  __shared__ bf16 LBg[2][2][128 * 32];
  int by, bx;
  xcd_map(blockIdx.x, XGM, BYG, BXG, by, bx);
  const size_t m0 = (size_t)by * 256, n0 = (size_t)bx * 128;
  const int t = threadIdx.x;
  const int w = t >> 6, lane = t & 63;
  const int wm = w >> 2, wn = w & 3;
  const int g = lane >> 4, r15 = lane & 15;
  const int nt = K >> 6;
  const int sr0 = t >> 2, ss0 = t & 3;
  const int sr1 = (t + 512) >> 2, ss1 = (t + 512) & 3;
  const int sc0 = ((ss0 ^ ((sr0 >> 1) & 3)) << 3);
  const int sc1 = ((ss1 ^ ((sr1 >> 1) & 3)) << 3);
  f32x4 av[8][2] = {}, ag[8][2] = {};

  auto stA = [&](int db, int kh, int st) {
    const bf16* src = A + m0 * K + (size_t)st * 64 + kh * 32;
    gload16(src + (size_t)sr0 * K + sc0, &LA[db][kh][t * 8]);
    gload16(src + (size_t)sr1 * K + sc1, &LA[db][kh][(t + 512) * 8]);
  };
  auto stBv = [&](int db, int kh, int st) {
    const bf16* src = BT + n0 * K + (size_t)st * 64 + kh * 32;
    gload16(src + (size_t)sr0 * K + sc0, &LBv[db][kh][t * 8]);
  };
  auto stBg = [&](int db, int kh, int st) {
    const bf16* src = BT + ((size_t)N + n0) * K + (size_t)st * 64 + kh * 32;
    gload16(src + (size_t)sr0 * K + sc0, &LBg[db][kh][t * 8]);
  };

  stA(0, 0, 0); stBv(0, 0, 0); stBg(0, 0, 0); stA(0, 1, 0); stBv(0, 1, 0); stBg(0, 1, 0);
  stA(1, 0, 1); stBv(1, 0, 1); stBg(1, 0, 1); stA(1, 1, 1);
  asm volatile("s_waitcnt vmcnt(10)" ::: "memory");
  __builtin_amdgcn_s_barrier();

  const int arow = wm * 128;

#define GEGLU_TILE(DD, TC)                                                                    \
  {                                                                                           \
    const int t1 = ((TC) + 1 < nt) ? (TC) + 1 : nt - 1;                                       \
    const int t2 = ((TC) + 2 < nt) ? (TC) + 2 : nt - 1;                                       \
    bf16x8 af[8], b0, b1;                                                                     \
    stBv((DD) ^ 1, 1, t1); stBg((DD) ^ 1, 1, t1);                                             \
    _Pragma("unroll")                                                                         \
    for (int mf = 0; mf < 8; ++mf) {                                                          \
      const int rr = arow + mf * 16 + r15;                                                    \
      af[mf] = *(const bf16x8*)&LA[DD][0][rr * 32 + ((g ^ ((rr >> 1) & 3)) << 3)];            \
    }                                                                                         \
    {                                                                                         \
      const int rb0 = wn * 32 + r15, rb1 = wn * 32 + 16 + r15;                                \
      b0 = *(const bf16x8*)&LBv[DD][0][rb0 * 32 + ((g ^ ((rb0 >> 1) & 3)) << 3)];             \
      b1 = *(const bf16x8*)&LBv[DD][0][rb1 * 32 + ((g ^ ((rb1 >> 1) & 3)) << 3)];             \
    }                                                                                         \
    __builtin_amdgcn_s_barrier();                                                             \
    __builtin_amdgcn_s_setprio(1);                                                            \
    _Pragma("unroll")                                                                         \
    for (int mf = 0; mf < 8; ++mf) {                                                          \
      av[mf][0] = MFMA16(af[mf], b0, av[mf][0]);                                              \
      av[mf][1] = MFMA16(af[mf], b1, av[mf][1]);                                              \
    }                                                                                         \
    __builtin_amdgcn_s_setprio(0);                                                            \
    stA(DD, 0, t2);                                                                           \
    {                                                                                         \
      const int rb0 = wn * 32 + r15, rb1 = wn * 32 + 16 + r15;                                \
      b0 = *(const bf16x8*)&LBg[DD][0][rb0 * 32 + ((g ^ ((rb0 >> 1) & 3)) << 3)];             \
      b1 = *(const bf16x8*)&LBg[DD][0][rb1 * 32 + ((g ^ ((rb1 >> 1) & 3)) << 3)];             \
    }                                                                                         \
    asm volatile("s_waitcnt vmcnt(10)" ::: "memory");                                         \
    __builtin_amdgcn_s_barrier();                                                             \
    __builtin_amdgcn_s_setprio(1);                                                            \
    _Pragma("unroll")                                                                         \
    for (int mf = 0; mf < 8; ++mf) {                                                          \
      ag[mf][0] = MFMA16(af[mf], b0, ag[mf][0]);                                              \
      ag[mf][1] = MFMA16(af[mf], b1, ag[mf][1]);                                              \
    }                                                                                         \
    __builtin_amdgcn_s_setprio(0);                                                            \
    stBv(DD, 0, t2); stBg(DD, 0, t2);                                                         \
    _Pragma("unroll")                                                                         \
    for (int mf = 0; mf < 8; ++mf) {                                                          \
      const int rr = arow + mf * 16 + r15;                                                    \
      af[mf] = *(const bf16x8*)&LA[DD][1][rr * 32 + ((g ^ ((rr >> 1) & 3)) << 3)];            \
    }                                                                                         \
    {                                                                                         \
      const int rb0 = wn * 32 + r15, rb1 = wn * 32 + 16 + r15;                                \
      b0 = *(const bf16x8*)&LBv[DD][1][rb0 * 32 + ((g ^ ((rb0 >> 1) & 3)) << 3)];             \
      b1 = *(const bf16x8*)&LBv[DD][1][rb1 * 32 + ((g ^ ((rb1 >> 1) & 3)) << 3)];             \
    }                                                                                         \
    __builtin_amdgcn_s_barrier();                                                             \
    __builtin_amdgcn_s_setprio(1);                                                            \
    _Pragma("unroll")                                                                         \
    for (int mf = 0; mf < 8; ++mf) {                                                          \
      av[mf][0] = MFMA16(af[mf], b0, av[mf][0]);                                              \
      av[mf][1] = MFMA16(af[mf], b1, av[mf][1]);                                              \
    }                                                                                         \
    __builtin_amdgcn_s_setprio(0);                                                            \
    stA(DD, 1, t2);                                                                           \
    {                                                                                         \
      const int rb0 = wn * 32 + r15, rb1 = wn * 32 + 16 + r15;                                \
      b0 = *(const bf16x8*)&LBg[DD][1][rb0 * 32 + ((g ^ ((rb0 >> 1) & 3)) << 3)];             \
      b1 = *(const bf16x8*)&LBg[DD][1][rb1 * 32 + ((g ^ ((rb1 >> 1) & 3)) << 3)];             \
    }                                                                                         \
    asm volatile("s_waitcnt vmcnt(10)" ::: "memory");                                         \
    __builtin_amdgcn_s_barrier();                                                             \
    __builtin_amdgcn_s_setprio(1);                                                            \
    _Pragma("unroll")                                                                         \
    for (int mf = 0; mf < 8; ++mf) {                                                          \
      ag[mf][0] = MFMA16(af[mf], b0, ag[mf][0]);                                              \
      ag[mf][1] = MFMA16(af[mf], b1, ag[mf][1]);                                              \
    }                                                                                         \
    __builtin_amdgcn_s_setprio(0);                                                            \
  }

  for (int tt = 0; tt < nt; tt += 2) {
    GEGLU_TILE(0, tt);
    GEGLU_TILE(1, tt + 1);
  }
#undef GEGLU_TILE

  #pragma unroll
  for (int mf = 0; mf < 8; ++mf)
    #pragma unroll
    for (int nf = 0; nf < 2; ++nf) {
      const size_t col = n0 + wn * 32 + nf * 16 + r15;
      #pragma unroll
      for (int rr = 0; rr < 4; ++rr) {
        const size_t row = m0 + wm * 128 + mf * 16 + g * 4 + rr;
        const float val = av[mf][nf][rr], gt = ag[mf][nf][rr];
        const float z = 1.595769122f * gt + 0.0713548162f * gt * gt * gt;
        const float gel = gt / (1.f + __expf(-z));
        G[row * (size_t)N + col] = (bf16)(val * gel);
      }
    }
}

// ---------------- 128x128 GEMM (m97 structure) for M=256 cases ----------------
template <int MODE>
__global__ __launch_bounds__(256) void k_gemm128(const bf16* __restrict__ A, const bf16* __restrict__ BT,
                                                 float* __restrict__ Cf, bf16* __restrict__ Cb,
                                                 int M, int N, int K) {
  __shared__ bf16 As[128 * 32];
  __shared__ bf16 Bs[128 * 32];
  const int t = threadIdx.x;
  const int lane = t & 63, w = t >> 6;
  const int wr = w >> 1, wc = w & 1;
  const int g = lane >> 4, r15 = lane & 15;
  const size_t m0 = (size_t)blockIdx.y * 128, n0 = (size_t)blockIdx.x * 128;
  f32x4 acc[4][4] = {};
  const int c0 = t, c1 = t + 256;
  const int ar0 = c0 >> 2, as0 = c0 & 3, ar1 = c1 >> 2, as1 = c1 & 3;
  const bf16* Ab = A + m0 * K;
  const bf16* Bb = BT + n0 * K;
  for (int k0 = 0; k0 < K; k0 += 32) {
    __syncthreads();
    gload16(Ab + (size_t)ar0 * K + k0 + ((as0 ^ (ar0 & 3)) << 3), &As[c0 * 8]);
    gload16(Ab + (size_t)ar1 * K + k0 + ((as1 ^ (ar1 & 3)) << 3), &As[c1 * 8]);
    gload16(Bb + (size_t)ar0 * K + k0 + ((as0 ^ (ar0 & 3)) << 3), &Bs[c0 * 8]);
    gload16(Bb + (size_t)ar1 * K + k0 + ((as1 ^ (ar1 & 3)) << 3), &Bs[c1 * 8]);
    __syncthreads();
    bf16x8 af[4], bfr[4];
    #pragma unroll
    for (int mi = 0; mi < 4; mi++) {
      int row = wr * 64 + mi * 16 + r15;
      af[mi] = *(const bf16x8*)&As[row * 32 + ((g ^ (row & 3)) << 3)];
    }
    #pragma unroll
    for (int ni = 0; ni < 4; ni++) {
      int row = wc * 64 + ni * 16 + r15;
      bfr[ni] = *(const bf16x8*)&Bs[row * 32 + ((g ^ (row & 3)) << 3)];
    }
    #pragma unroll
    for (int mi = 0; mi < 4; mi++)
      #pragma unroll
      for (int ni = 0; ni < 4; ni++)
        acc[mi][ni] = MFMA16(af[mi], bfr[ni], acc[mi][ni]);
  }
  #pragma unroll
  for (int mi = 0; mi < 4; mi++)
    #pragma unroll
    for (int ni = 0; ni < 4; ni++) {
      size_t col = n0 + wc * 64 + ni * 16 + r15;
      #pragma unroll
      for (int rr = 0; rr < 4; rr++) {
        size_t row = m0 + wr * 64 + mi * 16 + g * 4 + rr;
        size_t idx = row * (size_t)N + col;
        float v = acc[mi][ni][rr];
        if (MODE == 0) Cf[idx] = v;
        else Cb[idx] = (bf16)v;
      }
    }
}

// ---------------- flash attention (round-9 structure + exact defer-max; q pre-scaled) ------------
// grid (S/64, H), 4 waves x 16 q-rows, KVBLK=64, 40KB LDS.
__global__ __launch_bounds__(256) void k_attn(const bf16* __restrict__ Q, const bf16* __restrict__ Kb,
                                              const bf16* __restrict__ VT, bf16* __restrict__ O,
                                              int Skv) {
  __shared__ bf16 Kt[64 * 128];   // [key][d], 16 slots/row, slot ^= (key&15)
  __shared__ bf16 Vt[128 * 64];   // [d][key], 8 slots/row, slot ^= (d&7)
  __shared__ bf16 Pt[4][16 * 64]; // per-wave P, 8 slots/row, slot ^= (q&7)
  const int h = blockIdx.y;
  const int t = threadIdx.x, w = t >> 6, lane = t & 63;
  const int g = lane >> 4, r15 = lane & 15;
  const int q0 = blockIdx.x * 64 + w * 16;
  bf16x8 qf[4];
  #pragma unroll
  for (int c = 0; c < 4; c++)
    qf[c] = *(const bf16x8*)(Q + (size_t)(q0 + r15) * D + h * 128 + c * 32 + g * 8);
  f32x4 o[8] = {};
  float m_[4] = { -1e30f, -1e30f, -1e30f, -1e30f };
  float l_[4] = { 0.f, 0.f, 0.f, 0.f };
  for (int kt = 0; kt < Skv; kt += 64) {
    __syncthreads();
    #pragma unroll
    for (int cc = 0; cc < 4; cc++) {
      int c = t + cc * 256;
      int kr = c >> 4, ks = c & 15;
      gload16(Kb + (size_t)(kt + kr) * D + h * 128 + ((ks ^ (kr & 15)) << 3), &Kt[c * 8]);
      int vr = c >> 3, vs = c & 7;
      gload16(VT + (size_t)(h * 128 + vr) * Skv + kt + ((vs ^ (vr & 7)) << 3), &Vt[c * 8]);
    }
    __syncthreads();
    f32x4 s[4] = {};
    __builtin_amdgcn_s_setprio(1);
    #pragma unroll
    for (int c = 0; c < 4; c++) {
      #pragma unroll
      for (int j = 0; j < 4; j++) {
        const int row = j * 16 + r15;
        bf16x8 kf = *(const bf16x8*)&Kt[row * 128 + (((4 * c + g) ^ (row & 15)) << 3)];
        s[j] = MFMA16(qf[c], kf, s[j]);
      }
    }
    __builtin_amdgcn_s_setprio(0);
    float sv[4][4], mxs[4];
    bool grow = false;
    #pragma unroll
    for (int rr = 0; rr < 4; rr++) {
      sv[rr][0] = s[0][rr]; sv[rr][1] = s[1][rr]; sv[rr][2] = s[2][rr]; sv[rr][3] = s[3][rr];
      float mx = fmaxf(fmaxf(sv[rr][0], sv[rr][1]), fmaxf(sv[rr][2], sv[rr][3]));
      #pragma unroll
      for (int off = 1; off < 16; off <<= 1) mx = fmaxf(mx, __shfl_xor(mx, off, 16));
      mxs[rr] = mx;
      grow = grow || (mx > m_[rr]);
    }
    if (__any(grow ? 1 : 0)) {  // EXACT: when no row max grows, rescale factor is exp(0)=1
      float al[4];
      #pragma unroll
      for (int rr = 0; rr < 4; rr++) {
        float mn = fmaxf(m_[rr], mxs[rr]);
        al[rr] = __expf(m_[rr] - mn);
        l_[rr] *= al[rr];
        m_[rr] = mn;
      }
      #pragma unroll
      for (int d = 0; d < 8; d++)
        #pragma unroll
        for (int rr = 0; rr < 4; rr++) o[d][rr] *= al[rr];
    }
    #pragma unroll
    for (int rr = 0; rr < 4; rr++) {
      float p0 = __expf(sv[rr][0] - m_[rr]), p1 = __expf(sv[rr][1] - m_[rr]);
      float p2 = __expf(sv[rr][2] - m_[rr]), p3 = __expf(sv[rr][3] - m_[rr]);
      float sm = p0 + p1 + p2 + p3;
      #pragma unroll
      for (int off = 1; off < 16; off <<= 1) sm += __shfl_xor(sm, off, 16);
      l_[rr] += sm;
      const int prow = g * 4 + rr;
      const int sbase = prow * 64, sx = prow & 7, e = r15 & 7, hi = r15 >> 3;
      Pt[w][sbase + (((0 + hi) ^ sx) << 3) + e] = (bf16)p0;
      Pt[w][sbase + (((2 + hi) ^ sx) << 3) + e] = (bf16)p1;
      Pt[w][sbase + (((4 + hi) ^ sx) << 3) + e] = (bf16)p2;
      Pt[w][sbase + (((6 + hi) ^ sx) << 3) + e] = (bf16)p3;
    }
    bf16x8 pa[2];
    #pragma unroll
    for (int kk = 0; kk < 2; kk++)
      pa[kk] = *(const bf16x8*)&Pt[w][r15 * 64 + (((kk * 4 + g) ^ (r15 & 7)) << 3)];
    __builtin_amdgcn_s_setprio(1);
    #pragma unroll
    for (int d = 0; d < 8; d++) {
      const int vrow = d * 16 + r15;
      #pragma unroll
      for (int kk = 0; kk < 2; kk++) {
        bf16x8 vbf = *(const bf16x8*)&Vt[vrow * 64 + (((kk * 4 + g) ^ (vrow & 7)) << 3)];
        o[d] = MFMA16(pa[kk], vbf, o[d]);
      }
    }
    __builtin_amdgcn_s_setprio(0);
  }
  #pragma unroll
  for (int rr = 0; rr < 4; rr++) {
    float inv = 1.f / l_[rr];
    #pragma unroll
    for (int d = 0; d < 8; d++)
      O[(size_t)(q0 + g * 4 + rr) * D + h * 128 + d * 16 + r15] = (bf16)(o[d][rr] * inv);
  }
}

extern "C" void kernel_launch(void* const* d_in, const int* in_sizes, int n_in,
                              void* d_out, int out_size, void* d_ws, size_t ws_size,
                              hipStream_t stream) {
  (void)in_sizes; (void)n_in; (void)out_size; (void)ws_size;
  const float* video = (const float*)d_in[0];
  const float* text  = (const float*)d_in[1];
  const float* wq    = (const float*)d_in[2];
  const float* wk    = (const float*)d_in[3];
  const float* wv    = (const float*)d_in[4];
  const float* wo    = (const float*)d_in[5];
  const float* qnw   = (const float*)d_in[6];
  const float* knw   = (const float*)d_in[7];
  const float* cwq   = (const float*)d_in[8];
  const float* cwk   = (const float*)d_in[9];
  const float* cwv   = (const float*)d_in[10];
  const float* cwo   = (const float*)d_in[11];
  const float* cqnw  = (const float*)d_in[12];
  const float* cknw  = (const float*)d_in[13];
  const float* ffp   = (const float*)d_in[14];
  const float* ffd   = (const float*)d_in[15];
  float* out = (float*)d_out;
  const float SCQ = 0.08838834764831845f;  // 1/sqrt(128), folded into q

  char* slab = (char*)d_ws;
  const size_t MB = 1024 * 1024;
  bf16*  wbuf   = (bf16*)slab;
  bf16*  vt     = (bf16*)(slab + 96 * MB);
  bf16*  preqkv = (bf16*)(slab + 128 * MB);
  bf16*  Hval   = (bf16*)(slab + 268 * MB);
  char* p = slab + 402 * MB;
  auto take = [&](size_t bytes) { char* r = p; p += (bytes + 255) & ~(size_t)255; return r; };
  bf16* xb   = (bf16*)take((size_t)S * D * 2);
  bf16* qb   = (bf16*)take((size_t)S * D * 2);
  bf16* kb   = (bf16*)take((size_t)S * D * 2);
  bf16* ab   = (bf16*)take((size_t)S * D * 2);
  float* h1  = (float*)take((size_t)S * D * 4);
  bf16* tbuf = (bf16*)take((size_t)T * D * 2);
  bf16* ckb  = (bf16*)take((size_t)T * D * 2);
  bf16* cvb  = (bf16*)take((size_t)T * D * 2);
  bf16* cvt_ = (bf16*)take((size_t)T * D * 2);
  float* h2  = out;

  dim3 b256(256), b512(512), btc(64, 4), btb(32, 8);
  const int GRID_DD = 256, GRID_GG = 2048, GRID_QKV = 768;

  // ---- self-attention ----
  k_cvt<<<(S * D) / 1024, b256, 0, stream>>>(video, xb, S * D);
  k_tc<<<dim3(D / 64, D / 64), btc, 0, stream>>>(wq, wbuf, D, D, D);
  k_tc<<<dim3(D / 64, D / 64), btc, 0, stream>>>(wk, wbuf + (size_t)D * D, D, D, D);
  k_tc<<<dim3(D / 64, D / 64), btc, 0, stream>>>(wv, wbuf + 2 * (size_t)D * D, D, D, D);
  k_gemm2<1><<<GRID_QKV, b512, 0, stream>>>(xb, wbuf, nullptr, preqkv, nullptr, S, 3 * D, D, 2, 8, 12);
  k_rms<<<S, b256, 0, stream>>>(preqkv, qnw, qb, 3 * D, SCQ);
  k_rms<<<S, b256, 0, stream>>>(preqkv + D, knw, kb, 3 * D, 1.f);
  k_tb<<<dim3(D / 32, S / 32), btb, 0, stream>>>(preqkv + 2 * D, vt, S, D, 3 * D);
  k_attn<<<dim3(S / 64, H), b256, 0, stream>>>(qb, kb, vt, ab, S);
  k_tc<<<dim3(D / 64, D / 64), btc, 0, stream>>>(wo, wbuf, D, D, D);
  k_gemm2<3><<<GRID_DD, b512, 0, stream>>>(ab, wbuf, h1, xb, video, S, D, D, 2, 8, 4);

  // ---- cross-attention ----
  k_tc<<<dim3(D / 64, D / 64), btc, 0, stream>>>(cwq, wbuf, D, D, D);
  k_gemm2<1><<<GRID_DD, b512, 0, stream>>>(xb, wbuf, nullptr, preqkv, nullptr, S, D, D, 2, 8, 4);
  k_rms<<<S, b256, 0, stream>>>(preqkv, cqnw, qb, D, SCQ);
  k_cvt<<<(T * D) / 1024, b256, 0, stream>>>(text, tbuf, T * D);
  k_tc<<<dim3(D / 64, D / 64), btc, 0, stream>>>(cwk, wbuf, D, D, D);
  k_gemm128<1><<<dim3(D / 128, T / 128), b256, 0, stream>>>(tbuf, wbuf, nullptr, preqkv, T, D, D);
  k_rms<<<T, b256, 0, stream>>>(preqkv, cknw, ckb, D, 1.f);
  k_tc<<<dim3(D / 64, D / 64), btc, 0, stream>>>(cwv, wbuf, D, D, D);
  k_gemm128<1><<<dim3(D / 128, T / 128), b256, 0, stream>>>(tbuf, wbuf, nullptr, cvb, T, D, D);
  k_tb<<<dim3(D / 32, T / 32), btb, 0, stream>>>(cvb, cvt_, T, D, D);
  k_attn<<<dim3(S / 64, H), b256, 0, stream>>>(qb, ckb, cvt_, ab, T);
  k_tc<<<dim3(D / 64, D / 64), btc, 0, stream>>>(cwo, wbuf, D, D, D);
  k_gemm2<3><<<GRID_DD, b512, 0, stream>>>(ab, wbuf, h2, xb, h1, S, D, D, 2, 8, 4);

  // ---- GEGLU FFN (fused val+gate) ----
  k_tc<<<dim3((2 * F) / 64, D / 64), btc, 0, stream>>>(ffp, wbuf, D, 2 * F, 2 * F);
  k_geglu2<<<GRID_GG, b512, 0, stream>>>(xb, wbuf, Hval, F, D, 2, 8, 32);
  k_tc<<<dim3(D / 64, F / 64), btc, 0, stream>>>(ffd, wbuf, F, D, D);
  k_gemm2<2><<<GRID_DD, b512, 0, stream>>>(Hval, wbuf, out, nullptr, h2, S, D, F, 2, 8, 4);
}

// Round 15
// 3550.633 us; speedup vs baseline: 8.6042x; 1.0290x over previous
//
#include <hip/hip_runtime.h>
#include <cstdint>
#include <cstddef>

typedef __bf16 bf16;
typedef __bf16 bf16x8 __attribute__((ext_vector_type(8)));
typedef __bf16 bf16x4 __attribute__((ext_vector_type(4)));
typedef float f32x4 __attribute__((ext_vector_type(4)));

static constexpr int D = 4096;
static constexpr int S = 4096;
static constexpr int T = 256;
static constexpr int H = 32;
static constexpr int F = 16384;

__device__ __forceinline__ void gload16(const void* g, void* l) {
  __builtin_amdgcn_global_load_lds((const __attribute__((address_space(1))) void*)g,
                                   (__attribute__((address_space(3))) void*)l, 16, 0, 0);
}

#define MFMA16(a, b, c) __builtin_amdgcn_mfma_f32_16x16x32_bf16((a), (b), (c), 0, 0, 0)

// ---------------- elementwise f32 -> bf16 ----------------
__global__ __launch_bounds__(256) void k_cvt(const float* __restrict__ in, bf16* __restrict__ out, int n) {
  int i = (blockIdx.x * 256 + threadIdx.x) * 4;
  if (i >= n) return;
  float4 v = *(const float4*)(in + i);
  bf16x4 o = { (bf16)v.x, (bf16)v.y, (bf16)v.z, (bf16)v.w };
  *(bf16x4*)(out + i) = o;
}

// ---------------- transpose+cvt: f32 [R][C] (row stride ldin) -> bf16 [C][R], 64x64 tiles --------
__global__ __launch_bounds__(256) void k_tc(const float* __restrict__ in, bf16* __restrict__ out,
                                            int R, int C, int ldin) {
  __shared__ float tile[64][65];
  const int c0 = blockIdx.x * 64, r0 = blockIdx.y * 64;
  const int x = threadIdx.x, y = threadIdx.y;  // block (64,4)
  #pragma unroll
  for (int i = 0; i < 16; i++) {
    const int yy = y + 4 * i;
    tile[yy][x] = in[(size_t)(r0 + yy) * ldin + c0 + x];
  }
  __syncthreads();
  #pragma unroll
  for (int i = 0; i < 16; i++) {
    const int yy = y + 4 * i;
    out[(size_t)(c0 + yy) * R + r0 + x] = (bf16)tile[x][yy];
  }
}

// ---------------- batched transpose+cvt (up to 3 square DxD weights via blockIdx.z) --------------
__global__ __launch_bounds__(256) void k_tc3(const float* __restrict__ s0, const float* __restrict__ s1,
                                             const float* __restrict__ s2, bf16* __restrict__ d0,
                                             bf16* __restrict__ d1, bf16* __restrict__ d2) {
  const float* in = blockIdx.z == 0 ? s0 : (blockIdx.z == 1 ? s1 : s2);
  bf16* out = blockIdx.z == 0 ? d0 : (blockIdx.z == 1 ? d1 : d2);
  __shared__ float tile[64][65];
  const int c0 = blockIdx.x * 64, r0 = blockIdx.y * 64;
  const int x = threadIdx.x, y = threadIdx.y;
  #pragma unroll
  for (int i = 0; i < 16; i++) {
    const int yy = y + 4 * i;
    tile[yy][x] = in[(size_t)(r0 + yy) * D + c0 + x];
  }
  __syncthreads();
  #pragma unroll
  for (int i = 0; i < 16; i++) {
    const int yy = y + 4 * i;
    out[(size_t)(c0 + yy) * D + r0 + x] = (bf16)tile[x][yy];
  }
}

// ---------------- transpose bf16 [R][C] (row stride ldin) -> [C][R] ----------------
__global__ __launch_bounds__(256) void k_tb(const bf16* __restrict__ in, bf16* __restrict__ out,
                                            int R, int C, int ldin) {
  __shared__ bf16 tile[32][33];
  int c0 = blockIdx.x * 32, r0 = blockIdx.y * 32;
  int x = threadIdx.x, y = threadIdx.y;
  #pragma unroll
  for (int yy = y; yy < 32; yy += 8)
    tile[yy][x] = in[(size_t)(r0 + yy) * ldin + c0 + x];
  __syncthreads();
  #pragma unroll
  for (int yy = y; yy < 32; yy += 8)
    out[(size_t)(c0 + yy) * R + r0 + x] = tile[x][yy];
}

// ---------------- rmsnorm over 4096, bf16 in (row stride ldin) -> bf16 out, scaled ---------------
__global__ __launch_bounds__(256) void k_rms(const bf16* __restrict__ in, const float* __restrict__ w,
                                             bf16* __restrict__ out, int ldin, float sc) {
  const int row = blockIdx.x, t = threadIdx.x;
  const bf16* x = in + (size_t)row * ldin;
  float xv[16];
  float ss = 0.f;
  #pragma unroll
  for (int i = 0; i < 2; i++) {
    bf16x8 b = *(const bf16x8*)(x + t * 8 + i * 2048);
    #pragma unroll
    for (int j = 0; j < 8; j++) { xv[i * 8 + j] = (float)b[j]; ss += xv[i * 8 + j] * xv[i * 8 + j]; }
  }
  #pragma unroll
  for (int off = 1; off < 64; off <<= 1) ss += __shfl_xor(ss, off, 64);
  __shared__ float red[4];
  if ((t & 63) == 0) red[t >> 6] = ss;
  __syncthreads();
  float rms = rsqrtf((red[0] + red[1] + red[2] + red[3]) * (1.f / 4096.f) + 1e-6f) * sc;
  #pragma unroll
  for (int i = 0; i < 2; i++) {
    float4 w0 = *(const float4*)(w + t * 8 + i * 2048);
    float4 w1 = *(const float4*)(w + t * 8 + i * 2048 + 4);
    bf16x8 ov;
    ov[0] = (bf16)(xv[i * 8 + 0] * rms * w0.x); ov[1] = (bf16)(xv[i * 8 + 1] * rms * w0.y);
    ov[2] = (bf16)(xv[i * 8 + 2] * rms * w0.z); ov[3] = (bf16)(xv[i * 8 + 3] * rms * w0.w);
    ov[4] = (bf16)(xv[i * 8 + 4] * rms * w1.x); ov[5] = (bf16)(xv[i * 8 + 5] * rms * w1.y);
    ov[6] = (bf16)(xv[i * 8 + 6] * rms * w1.z); ov[7] = (bf16)(xv[i * 8 + 7] * rms * w1.w);
    *(bf16x8*)(out + (size_t)row * 4096 + t * 8 + i * 2048) = ov;
  }
}

// ---------------- dual rmsnorm (q with scale, k) from strided preqkv via blockIdx.y --------------
__global__ __launch_bounds__(256) void k_rms2(const bf16* __restrict__ in, const float* __restrict__ w0,
                                              const float* __restrict__ w1, bf16* __restrict__ out0,
                                              bf16* __restrict__ out1, int ldin, float sc0) {
  const int which = blockIdx.y;
  const float* w = which ? w1 : w0;
  bf16* out = which ? out1 : out0;
  const float sc = which ? 1.f : sc0;
  const int row = blockIdx.x, t = threadIdx.x;
  const bf16* x = in + (size_t)row * ldin + which * D;
  float xv[16];
  float ss = 0.f;
  #pragma unroll
  for (int i = 0; i < 2; i++) {
    bf16x8 b = *(const bf16x8*)(x + t * 8 + i * 2048);
    #pragma unroll
    for (int j = 0; j < 8; j++) { xv[i * 8 + j] = (float)b[j]; ss += xv[i * 8 + j] * xv[i * 8 + j]; }
  }
  #pragma unroll
  for (int off = 1; off < 64; off <<= 1) ss += __shfl_xor(ss, off, 64);
  __shared__ float red[4];
  if ((t & 63) == 0) red[t >> 6] = ss;
  __syncthreads();
  float rms = rsqrtf((red[0] + red[1] + red[2] + red[3]) * (1.f / 4096.f) + 1e-6f) * sc;
  #pragma unroll
  for (int i = 0; i < 2; i++) {
    float4 v0 = *(const float4*)(w + t * 8 + i * 2048);
    float4 v1 = *(const float4*)(w + t * 8 + i * 2048 + 4);
    bf16x8 ov;
    ov[0] = (bf16)(xv[i * 8 + 0] * rms * v0.x); ov[1] = (bf16)(xv[i * 8 + 1] * rms * v0.y);
    ov[2] = (bf16)(xv[i * 8 + 2] * rms * v0.z); ov[3] = (bf16)(xv[i * 8 + 3] * rms * v0.w);
    ov[4] = (bf16)(xv[i * 8 + 4] * rms * v1.x); ov[5] = (bf16)(xv[i * 8 + 5] * rms * v1.y);
    ov[6] = (bf16)(xv[i * 8 + 6] * rms * v1.z); ov[7] = (bf16)(xv[i * 8 + 7] * rms * v1.w);
    *(bf16x8*)(out + (size_t)row * 4096 + t * 8 + i * 2048) = ov;
  }
}

// supertile XCD mapping (bijective): by = (xcd%XGM)*BYG + oidx%BYG ; bx = (xcd/XGM)*BXG + oidx/BYG
__device__ __forceinline__ void xcd_map(int orig, int XGM, int BYG, int BXG, int& by, int& bx) {
  const int xcd = orig & 7, oidx = orig >> 3;
  by = (xcd % XGM) * BYG + oidx % BYG;
  bx = (xcd / XGM) * BXG + oidx / BYG;
}

// ================= 256x256 counted-vmcnt GEMM, 4 phases + kh1 A-frag prefetch ====================
// p0: {stB, read af(kh0)+b01, bar, MFMA nf01/kh0}; p1: {stA, read b23, vmcnt, bar, prefetch
// af2(kh1) inside MFMA nf23/kh0}; p2: {stB, read b01(kh1), bar, MFMA nf01/kh1 (af2 ready)};
// p3: {stA, read b23(kh1), vmcnt, bar, MFMA nf23/kh1}.  Stage/vmcnt cadence identical to r9.
// MODE 0: f32 out; 1: bf16 out; 2: f32 = v+res; 3: f32 = v+res AND bf16 dual write
template <int MODE>
__global__ __launch_bounds__(512, 2) void k_gemm2(const bf16* __restrict__ A, const bf16* __restrict__ BT,
                                                  float* __restrict__ Cf, bf16* __restrict__ Cb,
                                                  const float* __restrict__ res,
                                                  int M, int N, int K, int XGM, int BYG, int BXG) {
  __shared__ bf16 LA[2][2][256 * 32];  // [dbuf][kh][row*32+col]
  __shared__ bf16 LB[2][2][256 * 32];
  int by, bx;
  xcd_map(blockIdx.x, XGM, BYG, BXG, by, bx);
  const size_t m0 = (size_t)by * 256, n0 = (size_t)bx * 256;
  const int t = threadIdx.x;
  const int w = t >> 6, lane = t & 63;
  const int wm = w >> 2, wn = w & 3;
  const int g = lane >> 4, r15 = lane & 15;
  const int nt = K >> 6;
  const int sr0 = t >> 2, ss0 = t & 3;
  const int sr1 = (t + 512) >> 2, ss1 = (t + 512) & 3;
  const int sc0 = ((ss0 ^ ((sr0 >> 1) & 3)) << 3);
  const int sc1 = ((ss1 ^ ((sr1 >> 1) & 3)) << 3);
  f32x4 acc[8][4] = {};

  auto stA = [&](int db, int kh, int st) {
    const bf16* src = A + m0 * K + (size_t)st * 64 + kh * 32;
    gload16(src + (size_t)sr0 * K + sc0, &LA[db][kh][t * 8]);
    gload16(src + (size_t)sr1 * K + sc1, &LA[db][kh][(t + 512) * 8]);
  };
  auto stB = [&](int db, int kh, int st) {
    const bf16* src = BT + n0 * K + (size_t)st * 64 + kh * 32;
    gload16(src + (size_t)sr0 * K + sc0, &LB[db][kh][t * 8]);
    gload16(src + (size_t)sr1 * K + sc1, &LB[db][kh][(t + 512) * 8]);
  };

  stA(0, 0, 0); stB(0, 0, 0); stA(0, 1, 0); stB(0, 1, 0);
  stA(1, 0, 1); stB(1, 0, 1); stA(1, 1, 1);
  asm volatile("s_waitcnt vmcnt(10)" ::: "memory");
  __builtin_amdgcn_s_barrier();

  const int arow = wm * 128;

#define GEMM_TILE(DD, TC)                                                                     \
  {                                                                                           \
    const int t1 = ((TC) + 1 < nt) ? (TC) + 1 : nt - 1;                                       \
    const int t2 = ((TC) + 2 < nt) ? (TC) + 2 : nt - 1;                                       \
    bf16x8 af[8], af2[8], b0, b1;                                                             \
    /* phase 0: kh=0, nf01 */                                                                 \
    stB((DD) ^ 1, 1, t1);                                                                     \
    _Pragma("unroll")                                                                         \
    for (int mf = 0; mf < 8; ++mf) {                                                          \
      const int rr = arow + mf * 16 + r15;                                                    \
      af[mf] = *(const bf16x8*)&LA[DD][0][rr * 32 + ((g ^ ((rr >> 1) & 3)) << 3)];            \
    }                                                                                         \
    {                                                                                         \
      const int rb0 = wn * 64 + r15, rb1 = wn * 64 + 16 + r15;                                \
      b0 = *(const bf16x8*)&LB[DD][0][rb0 * 32 + ((g ^ ((rb0 >> 1) & 3)) << 3)];              \
      b1 = *(const bf16x8*)&LB[DD][0][rb1 * 32 + ((g ^ ((rb1 >> 1) & 3)) << 3)];              \
    }                                                                                         \
    __builtin_amdgcn_s_barrier();                                                             \
    __builtin_amdgcn_s_setprio(1);                                                            \
    _Pragma("unroll")                                                                         \
    for (int mf = 0; mf < 8; ++mf) {                                                          \
      acc[mf][0] = MFMA16(af[mf], b0, acc[mf][0]);                                            \
      acc[mf][1] = MFMA16(af[mf], b1, acc[mf][1]);                                            \
    }                                                                                         \
    __builtin_amdgcn_s_setprio(0);                                                            \
    /* phase 1: kh=0, nf23 + prefetch kh1 A-frags (kh1 landed per vmcnt below) */             \
    stA(DD, 0, t2);                                                                           \
    {                                                                                         \
      const int rb0 = wn * 64 + 32 + r15, rb1 = wn * 64 + 48 + r15;                           \
      b0 = *(const bf16x8*)&LB[DD][0][rb0 * 32 + ((g ^ ((rb0 >> 1) & 3)) << 3)];              \
      b1 = *(const bf16x8*)&LB[DD][0][rb1 * 32 + ((g ^ ((rb1 >> 1) & 3)) << 3)];              \
    }                                                                                         \
    asm volatile("s_waitcnt vmcnt(10)" ::: "memory");                                         \
    __builtin_amdgcn_s_barrier();                                                             \
    _Pragma("unroll")                                                                         \
    for (int mf = 0; mf < 8; ++mf) {                                                          \
      const int rr = arow + mf * 16 + r15;                                                    \
      af2[mf] = *(const bf16x8*)&LA[DD][1][rr * 32 + ((g ^ ((rr >> 1) & 3)) << 3)];           \
    }                                                                                         \
    __builtin_amdgcn_s_setprio(1);                                                            \
    _Pragma("unroll")                                                                         \
    for (int mf = 0; mf < 8; ++mf) {                                                          \
      acc[mf][2] = MFMA16(af[mf], b0, acc[mf][2]);                                            \
      acc[mf][3] = MFMA16(af[mf], b1, acc[mf][3]);                                            \
    }                                                                                         \
    __builtin_amdgcn_s_setprio(0);                                                            \
    /* phase 2: kh=1, nf01 (af2 already in regs) */                                           \
    stB(DD, 0, t2);                                                                           \
    {                                                                                         \
      const int rb0 = wn * 64 + r15, rb1 = wn * 64 + 16 + r15;                                \
      b0 = *(const bf16x8*)&LB[DD][1][rb0 * 32 + ((g ^ ((rb0 >> 1) & 3)) << 3)];              \
      b1 = *(const bf16x8*)&LB[DD][1][rb1 * 32 + ((g ^ ((rb1 >> 1) & 3)) << 3)];              \
    }                                                                                         \
    __builtin_amdgcn_s_barrier();                                                             \
    __builtin_amdgcn_s_setprio(1);                                                            \
    _Pragma("unroll")                                                                         \
    for (int mf = 0; mf < 8; ++mf) {                                                          \
      acc[mf][0] = MFMA16(af2[mf], b0, acc[mf][0]);                                           \
      acc[mf][1] = MFMA16(af2[mf], b1, acc[mf][1]);                                           \
    }                                                                                         \
    __builtin_amdgcn_s_setprio(0);                                                            \
    /* phase 3: kh=1, nf23 */                                                                 \
    stA(DD, 1, t2);                                                                           \
    {                                                                                         \
      const int rb0 = wn * 64 + 32 + r15, rb1 = wn * 64 + 48 + r15;                           \
      b0 = *(const bf16x8*)&LB[DD][1][rb0 * 32 + ((g ^ ((rb0 >> 1) & 3)) << 3)];              \
      b1 = *(const bf16x8*)&LB[DD][1][rb1 * 32 + ((g ^ ((rb1 >> 1) & 3)) << 3)];              \
    }                                                                                         \
    asm volatile("s_waitcnt vmcnt(10)" ::: "memory");                                         \
    __builtin_amdgcn_s_barrier();                                                             \
    __builtin_amdgcn_s_setprio(1);                                                            \
    _Pragma("unroll")                                                                         \
    for (int mf = 0; mf < 8; ++mf) {                                                          \
      acc[mf][2] = MFMA16(af2[mf], b0, acc[mf][2]);                                           \
      acc[mf][3] = MFMA16(af2[mf], b1, acc[mf][3]);                                           \
    }                                                                                         \
    __builtin_amdgcn_s_setprio(0);                                                            \
  }

  for (int tt = 0; tt < nt; tt += 2) {
    GEMM_TILE(0, tt);
    GEMM_TILE(1, tt + 1);
  }
#undef GEMM_TILE

  #pragma unroll
  for (int mf = 0; mf < 8; ++mf)
    #pragma unroll
    for (int nf = 0; nf < 4; ++nf) {
      const size_t col = n0 + wn * 64 + nf * 16 + r15;
      #pragma unroll
      for (int rr = 0; rr < 4; ++rr) {
        const size_t row = m0 + wm * 128 + mf * 16 + g * 4 + rr;
        const size_t idx = row * (size_t)N + col;
        const float v = acc[mf][nf][rr];
        if (MODE == 0) Cf[idx] = v;
        else if (MODE == 1) Cb[idx] = (bf16)v;
        else if (MODE == 2) Cf[idx] = v + res[idx];
        else { const float s = v + res[idx]; Cf[idx] = s; Cb[idx] = (bf16)s; }
      }
    }
}

// ================= fused GEGLU GEMM: tile 256x128, 4 phases + kh1 A-frag prefetch ================
__global__ __launch_bounds__(512, 2) void k_geglu2(const bf16* __restrict__ A, const bf16* __restrict__ BT,
                                                   bf16* __restrict__ G, int N, int K,
                                                   int XGM, int BYG, int BXG) {
  __shared__ bf16 LA[2][2][256 * 32];
  __shared__ bf16 LBv[2][2][128 * 32];
  __shared__ bf16 LBg[2][2][128 * 32];
  int by, bx;
  xcd_map(blockIdx.x, XGM, BYG, BXG, by, bx);
  const size_t m0 = (size_t)by * 256, n0 = (size_t)bx * 128;
  const int t = threadIdx.x;
  const int w = t >> 6, lane = t & 63;
  const int wm = w >> 2, wn = w & 3;
  const int g = lane >> 4, r15 = lane & 15;
  const int nt = K >> 6;
  const int sr0 = t >> 2, ss0 = t & 3;
  const int sr1 = (t + 512) >> 2, ss1 = (t + 512) & 3;
  const int sc0 = ((ss0 ^ ((sr0 >> 1) & 3)) << 3);
  const int sc1 = ((ss1 ^ ((sr1 >> 1) & 3)) << 3);
  f32x4 av[8][2] = {}, ag[8][2] = {};

  auto stA = [&](int db, int kh, int st) {
    const bf16* src = A + m0 * K + (size_t)st * 64 + kh * 32;
    gload16(src + (size_t)sr0 * K + sc0, &LA[db][kh][t * 8]);
    gload16(src + (size_t)sr1 * K + sc1, &LA[db][kh][(t + 512) * 8]);
  };
  auto stBv = [&](int db, int kh, int st) {
    const bf16* src = BT + n0 * K + (size_t)st * 64 + kh * 32;
    gload16(src + (size_t)sr0 * K + sc0, &LBv[db][kh][t * 8]);
  };
  auto stBg = [&](int db, int kh, int st) {
    const bf16* src = BT + ((size_t)N + n0) * K + (size_t)st * 64 + kh * 32;
    gload16(src + (size_t)sr0 * K + sc0, &LBg[db][kh][t * 8]);
  };

  stA(0, 0, 0); stBv(0, 0, 0); stBg(0, 0, 0); stA(0, 1, 0); stBv(0, 1, 0); stBg(0, 1, 0);
  stA(1, 0, 1); stBv(1, 0, 1); stBg(1, 0, 1); stA(1, 1, 1);
  asm volatile("s_waitcnt vmcnt(10)" ::: "memory");
  __builtin_amdgcn_s_barrier();

  const int arow = wm * 128;

#define GEGLU_TILE(DD, TC)                                                                    \
  {                                                                                           \
    const int t1 = ((TC) + 1 < nt) ? (TC) + 1 : nt - 1;                                       \
    const int t2 = ((TC) + 2 < nt) ? (TC) + 2 : nt - 1;                                       \
    bf16x8 af[8], af2[8], b0, b1;                                                             \
    /* phase 0: kh=0 val */                                                                   \
    stBv((DD) ^ 1, 1, t1); stBg((DD) ^ 1, 1, t1);                                             \
    _Pragma("unroll")                                                                         \
    for (int mf = 0; mf < 8; ++mf) {                                                          \
      const int rr = arow + mf * 16 + r15;                                                    \
      af[mf] = *(const bf16x8*)&LA[DD][0][rr * 32 + ((g ^ ((rr >> 1) & 3)) << 3)];            \
    }                                                                                         \
    {                                                                                         \
      const int rb0 = wn * 32 + r15, rb1 = wn * 32 + 16 + r15;                                \
      b0 = *(const bf16x8*)&LBv[DD][0][rb0 * 32 + ((g ^ ((rb0 >> 1) & 3)) << 3)];             \
      b1 = *(const bf16x8*)&LBv[DD][0][rb1 * 32 + ((g ^ ((rb1 >> 1) & 3)) << 3)];             \
    }                                                                                         \
    __builtin_amdgcn_s_barrier();                                                             \
    __builtin_amdgcn_s_setprio(1);                                                            \
    _Pragma("unroll")                                                                         \
    for (int mf = 0; mf < 8; ++mf) {                                                          \
      av[mf][0] = MFMA16(af[mf], b0, av[mf][0]);                                              \
      av[mf][1] = MFMA16(af[mf], b1, av[mf][1]);                                              \
    }                                                                                         \
    __builtin_amdgcn_s_setprio(0);                                                            \
    /* phase 1: kh=0 gate + prefetch kh1 A-frags */                                           \
    stA(DD, 0, t2);                                                                           \
    {                                                                                         \
      const int rb0 = wn * 32 + r15, rb1 = wn * 32 + 16 + r15;                                \
      b0 = *(const bf16x8*)&LBg[DD][0][rb0 * 32 + ((g ^ ((rb0 >> 1) & 3)) << 3)];             \
      b1 = *(const bf16x8*)&LBg[DD][0][rb1 * 32 + ((g ^ ((rb1 >> 1) & 3)) << 3)];             \
    }                                                                                         \
    asm volatile("s_waitcnt vmcnt(10)" ::: "memory");                                         \
    __builtin_amdgcn_s_barrier();                                                             \
    _Pragma("unroll")                                                                         \
    for (int mf = 0; mf < 8; ++mf) {                                                          \
      const int rr = arow + mf * 16 + r15;                                                    \
      af2[mf] = *(const bf16x8*)&LA[DD][1][rr * 32 + ((g ^ ((rr >> 1) & 3)) << 3)];           \
    }                                                                                         \
    __builtin_amdgcn_s_setprio(1);                                                            \
    _Pragma("unroll")                                                                         \
    for (int mf = 0; mf < 8; ++mf) {                                                          \
      ag[mf][0] = MFMA16(af[mf], b0, ag[mf][0]);                                              \
      ag[mf][1] = MFMA16(af[mf], b1, ag[mf][1]);                                              \
    }                                                                                         \
    __builtin_amdgcn_s_setprio(0);                                                            \
    /* phase 2: kh=1 val (af2 ready) */                                                       \
    stBv(DD, 0, t2); stBg(DD, 0, t2);                                                         \
    {                                                                                         \
      const int rb0 = wn * 32 + r15, rb1 = wn * 32 + 16 + r15;                                \
      b0 = *(const bf16x8*)&LBv[DD][1][rb0 * 32 + ((g ^ ((rb0 >> 1) & 3)) << 3)];             \
      b1 = *(const bf16x8*)&LBv[DD][1][rb1 * 32 + ((g ^ ((rb1 >> 1) & 3)) << 3)];             \
    }                                                                                         \
    __builtin_amdgcn_s_barrier();                                                             \
    __builtin_amdgcn_s_setprio(1);                                                            \
    _Pragma("unroll")                                                                         \
    for (int mf = 0; mf < 8; ++mf) {                                                          \
      av[mf][0] = MFMA16(af2[mf], b0, av[mf][0]);                                             \
      av[mf][1] = MFMA16(af2[mf], b1, av[mf][1]);                                             \
    }                                                                                         \
    __builtin_amdgcn_s_setprio(0);                                                            \
    /* phase 3: kh=1 gate */                                                                  \
    stA(DD, 1, t2);                                                                           \
    {                                                                                         \
      const int rb0 = wn * 32 + r15, rb1 = wn * 32 + 16 + r15;                                \
      b0 = *(const bf16x8*)&LBg[DD][1][rb0 * 32 + ((g ^ ((rb0 >> 1) & 3)) << 3)];             \
      b1 = *(const bf16x8*)&LBg[DD][1][rb1 * 32 + ((g ^ ((rb1 >> 1) & 3)) << 3)];             \
    }                                                                                         \
    asm volatile("s_waitcnt vmcnt(10)" ::: "memory");                                         \
    __builtin_amdgcn_s_barrier();                                                             \
    __builtin_amdgcn_s_setprio(1);                                                            \
    _Pragma("unroll")                                                                         \
    for (int mf = 0; mf < 8; ++mf) {                                                          \
      ag[mf][0] = MFMA16(af2[mf], b0, ag[mf][0]);                                             \
      ag[mf][1] = MFMA16(af2[mf], b1, ag[mf][1]);                                             \
    }                                                                                         \
    __builtin_amdgcn_s_setprio(0);                                                            \
  }

  for (int tt = 0; tt < nt; tt += 2) {
    GEGLU_TILE(0, tt);
    GEGLU_TILE(1, tt + 1);
  }
#undef GEGLU_TILE

  #pragma unroll
  for (int mf = 0; mf < 8; ++mf)
    #pragma unroll
    for (int nf = 0; nf < 2; ++nf) {
      const size_t col = n0 + wn * 32 + nf * 16 + r15;
      #pragma unroll
      for (int rr = 0; rr < 4; ++rr) {
        const size_t row = m0 + wm * 128 + mf * 16 + g * 4 + rr;
        const float val = av[mf][nf][rr], gt = ag[mf][nf][rr];
        const float z = 1.595769122f * gt + 0.0713548162f * gt * gt * gt;
        const float gel = gt / (1.f + __expf(-z));
        G[row * (size_t)N + col] = (bf16)(val * gel);
      }
    }
}

// ---------------- 128x128 GEMM (m97 structure) for M=256 cases ----------------
template <int MODE>
__global__ __launch_bounds__(256) void k_gemm128(const bf16* __restrict__ A, const bf16* __restrict__ BT,
                                                 float* __restrict__ Cf, bf16* __restrict__ Cb,
                                                 int M, int N, int K) {
  __shared__ bf16 As[128 * 32];
  __shared__ bf16 Bs[128 * 32];
  const int t = threadIdx.x;
  const int lane = t & 63, w = t >> 6;
  const int wr = w >> 1, wc = w & 1;
  const int g = lane >> 4, r15 = lane & 15;
  const size_t m0 = (size_t)blockIdx.y * 128, n0 = (size_t)blockIdx.x * 128;
  f32x4 acc[4][4] = {};
  const int c0 = t, c1 = t + 256;
  const int ar0 = c0 >> 2, as0 = c0 & 3, ar1 = c1 >> 2, as1 = c1 & 3;
  const bf16* Ab = A + m0 * K;
  const bf16* Bb = BT + n0 * K;
  for (int k0 = 0; k0 < K; k0 += 32) {
    __syncthreads();
    gload16(Ab + (size_t)ar0 * K + k0 + ((as0 ^ (ar0 & 3)) << 3), &As[c0 * 8]);
    gload16(Ab + (size_t)ar1 * K + k0 + ((as1 ^ (ar1 & 3)) << 3), &As[c1 * 8]);
    gload16(Bb + (size_t)ar0 * K + k0 + ((as0 ^ (ar0 & 3)) << 3), &Bs[c0 * 8]);
    gload16(Bb + (size_t)ar1 * K + k0 + ((as1 ^ (ar1 & 3)) << 3), &Bs[c1 * 8]);
    __syncthreads();
    bf16x8 af[4], bfr[4];
    #pragma unroll
    for (int mi = 0; mi < 4; mi++) {
      int row = wr * 64 + mi * 16 + r15;
      af[mi] = *(const bf16x8*)&As[row * 32 + ((g ^ (row & 3)) << 3)];
    }
    #pragma unroll
    for (int ni = 0; ni < 4; ni++) {
      int row = wc * 64 + ni * 16 + r15;
      bfr[ni] = *(const bf16x8*)&Bs[row * 32 + ((g ^ (row & 3)) << 3)];
    }
    #pragma unroll
    for (int mi = 0; mi < 4; mi++)
      #pragma unroll
      for (int ni = 0; ni < 4; ni++)
        acc[mi][ni] = MFMA16(af[mi], bfr[ni], acc[mi][ni]);
  }
  #pragma unroll
  for (int mi = 0; mi < 4; mi++)
    #pragma unroll
    for (int ni = 0; ni < 4; ni++) {
      size_t col = n0 + wc * 64 + ni * 16 + r15;
      #pragma unroll
      for (int rr = 0; rr < 4; rr++) {
        size_t row = m0 + wr * 64 + mi * 16 + g * 4 + rr;
        size_t idx = row * (size_t)N + col;
        float v = acc[mi][ni][rr];
        if (MODE == 0) Cf[idx] = v;
        else Cb[idx] = (bf16)v;
      }
    }
}

// ---------------- flash attention (round-9 structure + exact defer-max; q pre-scaled) ------------
__global__ __launch_bounds__(256) void k_attn(const bf16* __restrict__ Q, const bf16* __restrict__ Kb,
                                              const bf16* __restrict__ VT, bf16* __restrict__ O,
                                              int Skv) {
  __shared__ bf16 Kt[64 * 128];
  __shared__ bf16 Vt[128 * 64];
  __shared__ bf16 Pt[4][16 * 64];
  const int h = blockIdx.y;
  const int t = threadIdx.x, w = t >> 6, lane = t & 63;
  const int g = lane >> 4, r15 = lane & 15;
  const int q0 = blockIdx.x * 64 + w * 16;
  bf16x8 qf[4];
  #pragma unroll
  for (int c = 0; c < 4; c++)
    qf[c] = *(const bf16x8*)(Q + (size_t)(q0 + r15) * D + h * 128 + c * 32 + g * 8);
  f32x4 o[8] = {};
  float m_[4] = { -1e30f, -1e30f, -1e30f, -1e30f };
  float l_[4] = { 0.f, 0.f, 0.f, 0.f };
  for (int kt = 0; kt < Skv; kt += 64) {
    __syncthreads();
    #pragma unroll
    for (int cc = 0; cc < 4; cc++) {
      int c = t + cc * 256;
      int kr = c >> 4, ks = c & 15;
      gload16(Kb + (size_t)(kt + kr) * D + h * 128 + ((ks ^ (kr & 15)) << 3), &Kt[c * 8]);
      int vr = c >> 3, vs = c & 7;
      gload16(VT + (size_t)(h * 128 + vr) * Skv + kt + ((vs ^ (vr & 7)) << 3), &Vt[c * 8]);
    }
    __syncthreads();
    f32x4 s[4] = {};
    __builtin_amdgcn_s_setprio(1);
    #pragma unroll
    for (int c = 0; c < 4; c++) {
      #pragma unroll
      for (int j = 0; j < 4; j++) {
        const int row = j * 16 + r15;
        bf16x8 kf = *(const bf16x8*)&Kt[row * 128 + (((4 * c + g) ^ (row & 15)) << 3)];
        s[j] = MFMA16(qf[c], kf, s[j]);
      }
    }
    __builtin_amdgcn_s_setprio(0);
    float sv[4][4], mxs[4];
    bool grow = false;
    #pragma unroll
    for (int rr = 0; rr < 4; rr++) {
      sv[rr][0] = s[0][rr]; sv[rr][1] = s[1][rr]; sv[rr][2] = s[2][rr]; sv[rr][3] = s[3][rr];
      float mx = fmaxf(fmaxf(sv[rr][0], sv[rr][1]), fmaxf(sv[rr][2], sv[rr][3]));
      #pragma unroll
      for (int off = 1; off < 16; off <<= 1) mx = fmaxf(mx, __shfl_xor(mx, off, 16));
      mxs[rr] = mx;
      grow = grow || (mx > m_[rr]);
    }
    if (__any(grow ? 1 : 0)) {
      float al[4];
      #pragma unroll
      for (int rr = 0; rr < 4; rr++) {
        float mn = fmaxf(m_[rr], mxs[rr]);
        al[rr] = __expf(m_[rr] - mn);
        l_[rr] *= al[rr];
        m_[rr] = mn;
      }
      #pragma unroll
      for (int d = 0; d < 8; d++)
        #pragma unroll
        for (int rr = 0; rr < 4; rr++) o[d][rr] *= al[rr];
    }
    #pragma unroll
    for (int rr = 0; rr < 4; rr++) {
      float p0 = __expf(sv[rr][0] - m_[rr]), p1 = __expf(sv[rr][1] - m_[rr]);
      float p2 = __expf(sv[rr][2] - m_[rr]), p3 = __expf(sv[rr][3] - m_[rr]);
      float sm = p0 + p1 + p2 + p3;
      #pragma unroll
      for (int off = 1; off < 16; off <<= 1) sm += __shfl_xor(sm, off, 16);
      l_[rr] += sm;
      const int prow = g * 4 + rr;
      const int sbase = prow * 64, sx = prow & 7, e = r15 & 7, hi = r15 >> 3;
      Pt[w][sbase + (((0 + hi) ^ sx) << 3) + e] = (bf16)p0;
      Pt[w][sbase + (((2 + hi) ^ sx) << 3) + e] = (bf16)p1;
      Pt[w][sbase + (((4 + hi) ^ sx) << 3) + e] = (bf16)p2;
      Pt[w][sbase + (((6 + hi) ^ sx) << 3) + e] = (bf16)p3;
    }
    bf16x8 pa[2];
    #pragma unroll
    for (int kk = 0; kk < 2; kk++)
      pa[kk] = *(const bf16x8*)&Pt[w][r15 * 64 + (((kk * 4 + g) ^ (r15 & 7)) << 3)];
    __builtin_amdgcn_s_setprio(1);
    #pragma unroll
    for (int d = 0; d < 8; d++) {
      const int vrow = d * 16 + r15;
      #pragma unroll
      for (int kk = 0; kk < 2; kk++) {
        bf16x8 vbf = *(const bf16x8*)&Vt[vrow * 64 + (((kk * 4 + g) ^ (vrow & 7)) << 3)];
        o[d] = MFMA16(pa[kk], vbf, o[d]);
      }
    }
    __builtin_amdgcn_s_setprio(0);
  }
  #pragma unroll
  for (int rr = 0; rr < 4; rr++) {
    float inv = 1.f / l_[rr];
    #pragma unroll
    for (int d = 0; d < 8; d++)
      O[(size_t)(q0 + g * 4 + rr) * D + h * 128 + d * 16 + r15] = (bf16)(o[d][rr] * inv);
  }
}

extern "C" void kernel_launch(void* const* d_in, const int* in_sizes, int n_in,
                              void* d_out, int out_size, void* d_ws, size_t ws_size,
                              hipStream_t stream) {
  (void)in_sizes; (void)n_in; (void)out_size; (void)ws_size;
  const float* video = (const float*)d_in[0];
  const float* text  = (const float*)d_in[1];
  const float* wq    = (const float*)d_in[2];
  const float* wk    = (const float*)d_in[3];
  const float* wv    = (const float*)d_in[4];
  const float* wo    = (const float*)d_in[5];
  const float* qnw   = (const float*)d_in[6];
  const float* knw   = (const float*)d_in[7];
  const float* cwq   = (const float*)d_in[8];
  const float* cwk   = (const float*)d_in[9];
  const float* cwv   = (const float*)d_in[10];
  const float* cwo   = (const float*)d_in[11];
  const float* cqnw  = (const float*)d_in[12];
  const float* cknw  = (const float*)d_in[13];
  const float* ffp   = (const float*)d_in[14];
  const float* ffd   = (const float*)d_in[15];
  float* out = (float*)d_out;
  const float SCQ = 0.08838834764831845f;  // 1/sqrt(128), folded into q

  char* slab = (char*)d_ws;
  const size_t MB = 1024 * 1024;
  bf16*  wbuf   = (bf16*)slab;
  bf16*  vt     = (bf16*)(slab + 96 * MB);
  bf16*  preqkv = (bf16*)(slab + 128 * MB);
  bf16*  Hval   = (bf16*)(slab + 268 * MB);
  char* p = slab + 402 * MB;
  auto take = [&](size_t bytes) { char* r = p; p += (bytes + 255) & ~(size_t)255; return r; };
  bf16* xb   = (bf16*)take((size_t)S * D * 2);
  bf16* qb   = (bf16*)take((size_t)S * D * 2);
  bf16* kb   = (bf16*)take((size_t)S * D * 2);
  bf16* ab   = (bf16*)take((size_t)S * D * 2);
  float* h1  = (float*)take((size_t)S * D * 4);
  bf16* tbuf = (bf16*)take((size_t)T * D * 2);
  bf16* ckb  = (bf16*)take((size_t)T * D * 2);
  bf16* cvt_ = (bf16*)take((size_t)T * D * 2);
  float* h2  = out;

  dim3 b256(256), b512(512), btc(64, 4), btb(32, 8);
  const int GRID_DD = 256, GRID_GG = 2048, GRID_QKV = 768;

  // ---- self-attention ----
  k_cvt<<<(S * D) / 1024, b256, 0, stream>>>(video, xb, S * D);
  k_tc3<<<dim3(D / 64, D / 64, 3), btc, 0, stream>>>(wq, wk, wv, wbuf, wbuf + (size_t)D * D,
                                                     wbuf + 2 * (size_t)D * D);
  k_gemm2<1><<<GRID_QKV, b512, 0, stream>>>(xb, wbuf, nullptr, preqkv, nullptr, S, 3 * D, D, 2, 8, 12);
  k_rms2<<<dim3(S, 2), b256, 0, stream>>>(preqkv, qnw, knw, qb, kb, 3 * D, SCQ);
  k_tb<<<dim3(D / 32, S / 32), btb, 0, stream>>>(preqkv + 2 * D, vt, S, D, 3 * D);
  k_attn<<<dim3(S / 64, H), b256, 0, stream>>>(qb, kb, vt, ab, S);
  k_tc<<<dim3(D / 64, D / 64), btc, 0, stream>>>(wo, wbuf, D, D, D);
  k_gemm2<3><<<GRID_DD, b512, 0, stream>>>(ab, wbuf, h1, xb, video, S, D, D, 2, 8, 4);

  // ---- cross-attention ----
  k_tc<<<dim3(D / 64, D / 64), btc, 0, stream>>>(cwq, wbuf, D, D, D);
  k_gemm2<1><<<GRID_DD, b512, 0, stream>>>(xb, wbuf, nullptr, preqkv, nullptr, S, D, D, 2, 8, 4);
  k_rms<<<S, b256, 0, stream>>>(preqkv, cqnw, qb, D, SCQ);
  k_cvt<<<(T * D) / 1024, b256, 0, stream>>>(text, tbuf, T * D);
  k_tc3<<<dim3(D / 64, D / 64, 2), btc, 0, stream>>>(cwk, cwv, cwv, wbuf, wbuf + (size_t)D * D,
                                                     wbuf + (size_t)D * D);
  // merged K/V projection: [T][8192] (k cols 0..4095, v cols 4096..8191)
  k_gemm128<1><<<dim3((2 * D) / 128, T / 128), b256, 0, stream>>>(tbuf, wbuf, nullptr, preqkv, T, 2 * D, D);
  k_rms<<<T, b256, 0, stream>>>(preqkv, cknw, ckb, 2 * D, 1.f);
  k_tb<<<dim3(D / 32, T / 32), btb, 0, stream>>>(preqkv + D, cvt_, T, D, 2 * D);
  k_attn<<<dim3(S / 64, H), b256, 0, stream>>>(qb, ckb, cvt_, ab, T);
  k_tc<<<dim3(D / 64, D / 64), btc, 0, stream>>>(cwo, wbuf, D, D, D);
  k_gemm2<3><<<GRID_DD, b512, 0, stream>>>(ab, wbuf, h2, xb, h1, S, D, D, 2, 8, 4);

  // ---- GEGLU FFN (fused val+gate) ----
  k_tc<<<dim3((2 * F) / 64, D / 64), btc, 0, stream>>>(ffp, wbuf, D, 2 * F, 2 * F);
  k_geglu2<<<GRID_GG, b512, 0, stream>>>(xb, wbuf, Hval, F, D, 2, 8, 32);
  k_tc<<<dim3(D / 64, F / 64), btc, 0, stream>>>(ffd, wbuf, F, D, D);
  k_gemm2<2><<<GRID_DD, b512, 0, stream>>>(Hval, wbuf, out, nullptr, h2, S, D, F, 2, 8, 4);
}